// Round 1
// baseline (200.293 us; speedup 1.0000x reference)
//
#include <hip/hip_runtime.h>
#include <stdint.h>
#include <stddef.h>

// ---------------- constants ----------------
#define BATCH   16384
#define CDIM    13
#define NFEAT   26
#define VROWS   100000
#define EDIM    64
#define NEMB    27      // bottom + 26 embeddings
#define NINTER  351     // 27*26/2
#define TOPIN   2079    // 351 + 27*64
#define KP4     2080    // padded K for layer 4
#define BN_INVF 0.9999950000374997f

typedef __attribute__((ext_vector_type(8)))  __bf16 bf16x8;
typedef __attribute__((ext_vector_type(4)))  float  f32x4;
typedef __attribute__((ext_vector_type(16))) float  f32x16;
typedef __attribute__((ext_vector_type(4)))  uint32_t uint4v;

__device__ __forceinline__ uint32_t f2bf(float f){
  uint32_t u = __float_as_uint(f);
  return (u + 0x7fffu + ((u >> 16) & 1u)) >> 16;   // RNE
}
__device__ __forceinline__ uint32_t pack2(float a, float b){
  return f2bf(a) | (f2bf(b) << 16);
}
__device__ __forceinline__ void async_load16(const void* g, void* l){
  __builtin_amdgcn_global_load_lds(
      (const __attribute__((address_space(1))) uint32_t*)g,
      (__attribute__((address_space(3))) uint32_t*)l, 16, 0, 0);
}

// ---------------- prep: W[K][N] fp32 -> Wt[N][Kpad] bf16 (optional DLRM col remap) ----
// remap=1 (W4): out k<1728 -> src row 351+k (emb part); 1728<=k<2079 -> src row k-1728 (inter)
__global__ __launch_bounds__(256) void transposeW(
    const float* __restrict__ src, unsigned short* __restrict__ dst,
    int K, int N, int Kpad, int remap){
  __shared__ float tile[64][65];
  int k0 = blockIdx.x * 64, n0 = blockIdx.y * 64;
  int t = threadIdx.x;
  int srcBase = remap ? ((k0 < 1728) ? (k0 + 351) : (k0 - 1728)) : k0;
  #pragma unroll 4
  for(int p = 0; p < 16; p++){
    int kr = p*4 + (t >> 6), nc = t & 63;
    int kk = k0 + kr;
    float v = 0.f;
    if(kk < K && (n0 + nc) < N) v = src[(size_t)(srcBase + kr) * N + n0 + nc];
    tile[kr][nc] = v;
  }
  __syncthreads();
  #pragma unroll 4
  for(int p = 0; p < 16; p++){
    int nr = p*4 + (t >> 6), kc = t & 63;
    int kk = k0 + kc;
    if(kk < Kpad && (n0 + nr) < N)
      dst[(size_t)(n0 + nr) * Kpad + kk] = (unsigned short)f2bf(tile[kc][nr]);
  }
}

// ---------------- bottom MLP: 13 -> 256 -> 128 -> 64 (fp32, fused) ----------------
__global__ __launch_bounds__(256) void bottom_mlp(
    const float* __restrict__ cont,
    const float* __restrict__ W1, const float* __restrict__ b1,
    const float* __restrict__ g1, const float* __restrict__ be1,
    const float* __restrict__ W2, const float* __restrict__ b2,
    const float* __restrict__ g2, const float* __restrict__ be2,
    const float* __restrict__ W3, const float* __restrict__ b3,
    float* __restrict__ bottomF){
  __shared__ float xs[32*13];
  __shared__ float h1[32*256];
  __shared__ float h2[32*128];
  int t = threadIdx.x;
  int b0 = blockIdx.x * 32;
  for(int i = t; i < 32*13; i += 256) xs[i] = cont[(size_t)b0*13 + i];
  __syncthreads();
  { // layer 1: N=256, thread owns one column
    float wv[13];
    #pragma unroll
    for(int k = 0; k < 13; k++) wv[k] = W1[k*256 + t];
    float sc = g1[t]*BN_INVF, bo = be1[t], bi = b1[t];
    for(int r = 0; r < 32; r++){
      float a = bi;
      #pragma unroll
      for(int k = 0; k < 13; k++) a = fmaf(xs[r*13+k], wv[k], a);
      h1[r*256 + t] = fmaxf(sc*a + bo, 0.f);
    }
  }
  __syncthreads();
  { // layer 2: N=128, thread -> (col, 16-row group)
    int c = t & 127, rb = (t >> 7) * 16;
    float acc2[16];
    float bi = b2[c];
    #pragma unroll
    for(int r = 0; r < 16; r++) acc2[r] = bi;
    for(int kc = 0; kc < 8; kc++){
      float wv[32];
      #pragma unroll
      for(int i = 0; i < 32; i++) wv[i] = W2[(kc*32 + i)*128 + c];
      #pragma unroll
      for(int r = 0; r < 16; r++){
        #pragma unroll
        for(int i = 0; i < 32; i++)
          acc2[r] = fmaf(h1[(rb+r)*256 + kc*32 + i], wv[i], acc2[r]);
      }
    }
    float sc = g2[c]*BN_INVF, bo = be2[c];
    #pragma unroll
    for(int r = 0; r < 16; r++) h2[(rb+r)*128 + c] = fmaxf(sc*acc2[r] + bo, 0.f);
  }
  __syncthreads();
  { // layer 3: N=64, plain linear (no BN/ReLU)
    int c = t & 63, rb = (t >> 6) * 8;
    float acc3[8];
    float bi = b3[c];
    #pragma unroll
    for(int r = 0; r < 8; r++) acc3[r] = bi;
    for(int kc = 0; kc < 4; kc++){
      float wv[32];
      #pragma unroll
      for(int i = 0; i < 32; i++) wv[i] = W3[(kc*32 + i)*64 + c];
      #pragma unroll
      for(int r = 0; r < 8; r++){
        #pragma unroll
        for(int i = 0; i < 32; i++)
          acc3[r] = fmaf(h2[(rb+r)*128 + kc*32 + i], wv[i], acc3[r]);
      }
    }
    for(int r = 0; r < 8; r++)
      bottomF[(size_t)(b0 + rb + r)*64 + c] = acc3[r];
  }
}

// ---------------- interact: gather + Z=E·E^T (one wave per sample) --------------
// top_in layout per row (KP4=2080 bf16): [ all_emb flat 0..1727 | inter 1728..2078 | pad 2079=0 ]
__global__ __launch_bounds__(256) void interact(
    const float* __restrict__ bottomF, const int* __restrict__ cat_idx,
    const float* __restrict__ emb, unsigned short* __restrict__ top_in){
  __shared__ unsigned short inter_s[4][352];
  int w = threadIdx.x >> 6, l = threadIdx.x & 63;
  int b = blockIdx.x * 4 + w;
  int r = l & 31, h = l >> 5;   // r = row/col of E, h = k-half
  const float* src = bottomF;   // dummy for inactive lanes
  bool active = (r < NEMB);
  if(active){
    if(r == 0) src = bottomF + (size_t)b * 64;
    else {
      int f = r - 1;
      int idx = cat_idx[b * NFEAT + f];
      src = emb + ((size_t)f * VROWS + (size_t)idx) * 64;
    }
  }
  uint4v q[4];
  #pragma unroll
  for(int s = 0; s < 4; s++){
    if(active){
      int k0 = h*8 + s*16;
      float4 v0 = *(const float4*)(src + k0);
      float4 v1 = *(const float4*)(src + k0 + 4);
      q[s][0] = pack2(v0.x, v0.y); q[s][1] = pack2(v0.z, v0.w);
      q[s][2] = pack2(v1.x, v1.y); q[s][3] = pack2(v1.z, v1.w);
    } else {
      q[s][0] = 0; q[s][1] = 0; q[s][2] = 0; q[s][3] = 0;
    }
  }
  // write all_emb section (16B aligned: base = b*4160 bytes)
  if(active){
    #pragma unroll
    for(int s = 0; s < 4; s++)
      *(uint4v*)(top_in + (size_t)b*KP4 + r*64 + h*8 + s*16) = q[s];
  }
  // Z = E * E^T via 4x mfma_32x32x16 (A-frag == B-frag)
  f32x16 acc;
  #pragma unroll
  for(int i = 0; i < 16; i++) acc[i] = 0.f;
  #pragma unroll
  for(int s = 0; s < 4; s++){
    bf16x8 a = __builtin_bit_cast(bf16x8, q[s]);
    acc = __builtin_amdgcn_mfma_f32_32x32x16_bf16(a, a, acc, 0, 0, 0);
  }
  // extract upper triangle: lane holds Z[i][j] with j = r (col), i from reg layout
  if(active){
    #pragma unroll
    for(int qq = 0; qq < 16; qq++){
      int i = (qq & 3) + 8*(qq >> 2) + 4*h;
      if(i < r){
        int p = i*(53 - i)/2 + (r - i - 1);
        inter_s[w][p] = (unsigned short)f2bf(acc[qq]);
      }
    }
  }
  __syncthreads();
  size_t basei = (size_t)b*KP4 + 1728;
  for(int t0 = l; t0 < 176; t0 += 64){
    uint32_t lo = inter_s[w][2*t0];
    uint32_t hi = (2*t0 + 1 < NINTER) ? (uint32_t)inter_s[w][2*t0 + 1] : 0u;  // elem 2079 = pad 0
    *(uint32_t*)(top_in + basei + 2*t0) = lo | (hi << 16);
  }
}

// ---------------- MFMA GEMM (m97 structure): C[128xBN-tile] = A[M,K]bf16 @ Wt[N,K]bf16^T
// epilogue: relu(g*BN_INV*(acc+b)+be) -> bf16 out; FUSE: also layer-7 dot -> scores
template<int KSTEPS, bool FUSE>
__global__ __launch_bounds__(256) void gemm_top(
    const unsigned short* __restrict__ A, int sA,
    const unsigned short* __restrict__ Bw, int sB,
    const float* __restrict__ bias, const float* __restrict__ gg,
    const float* __restrict__ be,
    unsigned short* __restrict__ out, int sOut,
    const float* __restrict__ W7, const float* __restrict__ b7,
    float* __restrict__ scores){
  __shared__ unsigned short As[128*32];
  __shared__ unsigned short Bs[128*32];
  __shared__ float h6s[FUSE ? 128*132 : 1];
  __shared__ float w7s[FUSE ? 128 : 1];
  int m0 = blockIdx.x * 128, n0 = blockIdx.y * 128;
  int t = threadIdx.x, w = t >> 6, l = t & 63;
  int wr = (w >> 1) * 64, wc = (w & 1) * 64;
  f32x4 acc[4][4];
  #pragma unroll
  for(int i = 0; i < 4; i++)
    #pragma unroll
    for(int j = 0; j < 4; j++)
      #pragma unroll
      for(int e = 0; e < 4; e++) acc[i][j][e] = 0.f;

  // staging addresses: LDS tile row = 32 bf16 = 64B; per thread 2 issues for A, 2 for B
  int off0 = w*2048 + l*16;
  int row0 = off0 >> 6, ce0 = (off0 & 63) >> 1;
  int off1 = off0 + 1024;
  int row1 = off1 >> 6, ce1 = (off1 & 63) >> 1;
  const unsigned short* gA0 = A  + (size_t)(m0 + row0)*sA + ce0;
  const unsigned short* gA1 = A  + (size_t)(m0 + row1)*sA + ce1;
  const unsigned short* gB0 = Bw + (size_t)(n0 + row0)*sB + ce0;
  const unsigned short* gB1 = Bw + (size_t)(n0 + row1)*sB + ce1;
  char* ldsA0 = (char*)As + w*2048;
  char* ldsA1 = (char*)As + w*2048 + 1024;
  char* ldsB0 = (char*)Bs + w*2048;
  char* ldsB1 = (char*)Bs + w*2048 + 1024;
  int lr = l & 15;
  int lkb = (l >> 4) * 16;   // byte offset of 8-bf16 k-chunk in a 64B row

  for(int kt = 0; kt < KSTEPS; kt++){
    async_load16(gA0 + kt*32, ldsA0);
    async_load16(gA1 + kt*32, ldsA1);
    async_load16(gB0 + kt*32, ldsB0);
    async_load16(gB1 + kt*32, ldsB1);
    __syncthreads();   // drains vmcnt(0) before barrier
    bf16x8 af[4], bfr[4];
    #pragma unroll
    for(int x = 0; x < 4; x++){
      af[x]  = *(const bf16x8*)((const char*)As + (wr + x*16 + lr)*64 + lkb);
      bfr[x] = *(const bf16x8*)((const char*)Bs + (wc + x*16 + lr)*64 + lkb);
    }
    #pragma unroll
    for(int tr = 0; tr < 4; tr++)
      #pragma unroll
      for(int tc = 0; tc < 4; tc++)
        acc[tr][tc] = __builtin_amdgcn_mfma_f32_16x16x32_bf16(af[tr], bfr[tc], acc[tr][tc], 0, 0, 0);
    __syncthreads();
  }

  if constexpr(!FUSE){
    #pragma unroll
    for(int tc = 0; tc < 4; tc++){
      int n = n0 + wc + tc*16 + lr;
      float sc = gg[n]*BN_INVF, bo = be[n], bi = bias[n];
      #pragma unroll
      for(int tr = 0; tr < 4; tr++){
        int mb = m0 + wr + tr*16 + (l >> 4)*4;
        #pragma unroll
        for(int qq = 0; qq < 4; qq++){
          float y = fmaxf(sc*(acc[tr][tc][qq] + bi) + bo, 0.f);
          out[(size_t)(mb + qq)*sOut + n] = (unsigned short)f2bf(y);
        }
      }
    }
  } else {
    if(t < 128) w7s[t] = W7[t];
    #pragma unroll
    for(int tc = 0; tc < 4; tc++){
      int n = wc + tc*16 + lr;
      float sc = gg[n0+n]*BN_INVF, bo = be[n0+n], bi = bias[n0+n];
      #pragma unroll
      for(int tr = 0; tr < 4; tr++){
        int mb = wr + tr*16 + (l >> 4)*4;
        #pragma unroll
        for(int qq = 0; qq < 4; qq++)
          h6s[(mb + qq)*132 + n] = fmaxf(sc*(acc[tr][tc][qq] + bi) + bo, 0.f);
      }
    }
    __syncthreads();
    if(t < 128){
      float a7 = b7[0];
      #pragma unroll 8
      for(int c = 0; c < 128; c++) a7 = fmaf(h6s[t*132 + c], w7s[c], a7);
      scores[m0 + t] = a7;
    }
  }
}

// ---------------- launch ----------------
static inline size_t alignup(size_t x){ return (x + 255) & ~(size_t)255; }

extern "C" void kernel_launch(void* const* d_in, const int* in_sizes, int n_in,
                              void* d_out, int out_size, void* d_ws, size_t ws_size,
                              hipStream_t stream){
  const float* cont = (const float*)d_in[0];
  const int*   cat  = (const int*)  d_in[1];
  const float* emb  = (const float*)d_in[2];
  const float* W1 = (const float*)d_in[3],  *b1 = (const float*)d_in[4];
  const float* g1 = (const float*)d_in[5],  *be1= (const float*)d_in[6];
  const float* W2 = (const float*)d_in[7],  *b2 = (const float*)d_in[8];
  const float* g2 = (const float*)d_in[9],  *be2= (const float*)d_in[10];
  const float* W3 = (const float*)d_in[11], *b3 = (const float*)d_in[12];
  const float* W4 = (const float*)d_in[13], *b4 = (const float*)d_in[14];
  const float* g4 = (const float*)d_in[15], *be4= (const float*)d_in[16];
  const float* W5 = (const float*)d_in[17], *b5 = (const float*)d_in[18];
  const float* g5 = (const float*)d_in[19], *be5= (const float*)d_in[20];
  const float* W6 = (const float*)d_in[21], *b6 = (const float*)d_in[22];
  const float* g6 = (const float*)d_in[23], *be6= (const float*)d_in[24];
  const float* W7 = (const float*)d_in[25], *b7 = (const float*)d_in[26];

  char* ws = (char*)d_ws;
  float* bottomF       = (float*)ws;          ws += alignup((size_t)BATCH*64*4);
  unsigned short* topi = (unsigned short*)ws; ws += alignup((size_t)BATCH*KP4*2);
  unsigned short* W4t  = (unsigned short*)ws; ws += alignup((size_t)512*KP4*2);
  unsigned short* W5t  = (unsigned short*)ws; ws += alignup((size_t)256*512*2);
  unsigned short* W6t  = (unsigned short*)ws; ws += alignup((size_t)128*256*2);
  unsigned short* h4   = (unsigned short*)ws; ws += alignup((size_t)BATCH*512*2);
  unsigned short* h5   = (unsigned short*)ws; ws += alignup((size_t)BATCH*256*2);
  (void)ws_size; (void)n_in; (void)in_sizes; (void)out_size;

  // weight preps (bf16 transpose; W4 with DLRM column remap + K-pad zeros)
  hipLaunchKernelGGL(transposeW, dim3(33, 8), dim3(256), 0, stream, W4, W4t, TOPIN, 512, KP4, 1);
  hipLaunchKernelGGL(transposeW, dim3(8, 4),  dim3(256), 0, stream, W5, W5t, 512, 256, 512, 0);
  hipLaunchKernelGGL(transposeW, dim3(4, 2),  dim3(256), 0, stream, W6, W6t, 256, 128, 256, 0);
  // bottom MLP (fp32)
  hipLaunchKernelGGL(bottom_mlp, dim3(512), dim3(256), 0, stream,
                     cont, W1, b1, g1, be1, W2, b2, g2, be2, W3, b3, bottomF);
  // gather + interactions -> top_in (bf16)
  hipLaunchKernelGGL(interact, dim3(BATCH/4), dim3(256), 0, stream, bottomF, cat, emb, topi);
  // top MLP
  hipLaunchKernelGGL((gemm_top<KP4/32, false>), dim3(128, 4), dim3(256), 0, stream,
                     topi, KP4, W4t, KP4, b4, g4, be4, h4, 512,
                     (const float*)nullptr, (const float*)nullptr, (float*)nullptr);
  hipLaunchKernelGGL((gemm_top<16, false>), dim3(128, 2), dim3(256), 0, stream,
                     h4, 512, W5t, 512, b5, g5, be5, h5, 256,
                     (const float*)nullptr, (const float*)nullptr, (float*)nullptr);
  hipLaunchKernelGGL((gemm_top<8, true>), dim3(128, 1), dim3(256), 0, stream,
                     h5, 256, W6t, 256, b6, g6, be6, (unsigned short*)nullptr, 0,
                     W7, b7, (float*)d_out);
}

// Round 2
// 145.496 us; speedup vs baseline: 1.3766x; 1.3766x over previous
//
#include <hip/hip_runtime.h>
#include <stdint.h>
#include <stddef.h>

// ---------------- constants ----------------
#define BATCH   16384
#define CDIM    13
#define NFEAT   26
#define VROWS   100000
#define EDIM    64
#define NEMB    27      // bottom + 26 embeddings
#define NINTER  351     // 27*26/2
#define TOPIN   2079    // 351 + 27*64
#define KP4     2080    // padded K for layer 4
#define BN_INVF 0.9999950000374997f

typedef __attribute__((ext_vector_type(8)))  __bf16 bf16x8;
typedef __attribute__((ext_vector_type(4)))  float  f32x4;
typedef __attribute__((ext_vector_type(16))) float  f32x16;
typedef __attribute__((ext_vector_type(4)))  uint32_t uint4v;

__device__ __forceinline__ uint32_t f2bf(float f){
  uint32_t u = __float_as_uint(f);
  return (u + 0x7fffu + ((u >> 16) & 1u)) >> 16;   // RNE
}
__device__ __forceinline__ float bf2f(uint32_t h){ return __uint_as_float(h << 16); }
__device__ __forceinline__ uint32_t pack2(float a, float b){
  return f2bf(a) | (f2bf(b) << 16);
}
__device__ __forceinline__ void async_load16(const void* g, void* l){
  __builtin_amdgcn_global_load_lds(
      (const __attribute__((address_space(1))) uint32_t*)g,
      (__attribute__((address_space(3))) uint32_t*)l, 16, 0, 0);
}
// activation-LDS row swizzle: XOR of element index bits 3..5, injective per row,
// spreads both 16-consecutive-row frag reads and 4-strided epilogue writes
__device__ __forceinline__ int rswz(int row){ return ((row ^ (row >> 3)) & 7) << 3; }

// ---------------- prep: all weight transposes + x hi/lo split (one launch) ----
__device__ __forceinline__ void transpose_tile(
    float (*tile)[65], const float* __restrict__ src, unsigned short* __restrict__ dst,
    int K, int N, int Kpad, int remap, int kb, int nb){
  int k0 = kb*64, n0 = nb*64, t = threadIdx.x;
  int srcBase = remap ? ((k0 < 1728) ? (k0 + 351) : (k0 - 1728)) : k0;
  #pragma unroll 4
  for(int p = 0; p < 16; p++){
    int kr = p*4 + (t >> 6), nc = t & 63;
    float v = 0.f;
    if(k0 + kr < K && (n0 + nc) < N) v = src[(size_t)(srcBase + kr) * N + n0 + nc];
    tile[kr][nc] = v;
  }
  __syncthreads();
  #pragma unroll 4
  for(int p = 0; p < 16; p++){
    int nr = p*4 + (t >> 6), kc = t & 63;
    if(k0 + kc < Kpad && (n0 + nr) < N)
      dst[(size_t)(n0 + nr) * Kpad + k0 + kc] = (unsigned short)f2bf(tile[kc][nr]);
  }
}

__global__ __launch_bounds__(256) void prep(
    const float* __restrict__ cont,
    const float* __restrict__ W1, const float* __restrict__ W2, const float* __restrict__ W3,
    const float* __restrict__ W4, const float* __restrict__ W5, const float* __restrict__ W6,
    unsigned short* __restrict__ xphi, unsigned short* __restrict__ xplo,
    unsigned short* __restrict__ W1t, unsigned short* __restrict__ W2t,
    unsigned short* __restrict__ W3t, unsigned short* __restrict__ W4t,
    unsigned short* __restrict__ W5t, unsigned short* __restrict__ W6t){
  __shared__ float tile[64][65];
  int bid = blockIdx.x;
  if(bid < 264){ transpose_tile(tile, W4, W4t, TOPIN, 512, KP4, 1, bid % 33, bid / 33); }
  else if(bid < 296){ int r = bid-264; transpose_tile(tile, W5, W5t, 512, 256, 512, 0, r % 8, r / 8); }
  else if(bid < 304){ int r = bid-296; transpose_tile(tile, W6, W6t, 256, 128, 256, 0, r % 4, r / 4); }
  else if(bid < 312){ int r = bid-304; transpose_tile(tile, W2, W2t, 256, 128, 256, 0, r % 4, r / 4); }
  else if(bid < 314){ int r = bid-312; transpose_tile(tile, W3, W3t, 128, 64, 128, 0, r, 0); }
  else if(bid < 318){ int r = bid-314; transpose_tile(tile, W1, W1t, CDIM, 256, 32, 0, 0, r); }
  else {
    // x -> hi/lo bf16, padded 13 -> 32
    int row = (bid - 318) * 256 + threadIdx.x;
    const float* xr = cont + (size_t)row * CDIM;
    uint32_t uh[16], ul[16];
    #pragma unroll
    for(int k = 0; k < 16; k++){
      uint32_t h0=0, h1=0, l0=0, l1=0;
      if(2*k < CDIM){
        float x = xr[2*k]; h0 = f2bf(x); l0 = f2bf(x - bf2f(h0));
      }
      if(2*k+1 < CDIM){
        float x = xr[2*k+1]; h1 = f2bf(x); l1 = f2bf(x - bf2f(h1));
      }
      uh[k] = h0 | (h1 << 16);
      ul[k] = l0 | (l1 << 16);
    }
    #pragma unroll
    for(int s = 0; s < 4; s++){
      uint4v vh, vl;
      #pragma unroll
      for(int e = 0; e < 4; e++){ vh[e] = uh[4*s+e]; vl[e] = ul[4*s+e]; }
      *(uint4v*)(xphi + (size_t)row*32 + s*8) = vh;
      *(uint4v*)(xplo + (size_t)row*32 + s*8) = vl;
    }
  }
}

// ---------------- bottom MLP via MFMA, hi/lo-compensated activations ----------
// block = 64 batch rows, 4 waves; grid 256
__global__ __launch_bounds__(256) void bottom_mfma(
    const unsigned short* __restrict__ xphi, const unsigned short* __restrict__ xplo,
    const unsigned short* __restrict__ W1t, const unsigned short* __restrict__ W2t,
    const unsigned short* __restrict__ W3t,
    const float* __restrict__ b1, const float* __restrict__ g1, const float* __restrict__ be1,
    const float* __restrict__ b2, const float* __restrict__ g2, const float* __restrict__ be2,
    const float* __restrict__ b3,
    unsigned short* __restrict__ bottomBF){
  __shared__ unsigned short h1hi[64*256];   // 32 KB (row-swizzled)
  __shared__ unsigned short h1lo[64*256];   // 32 KB
  __shared__ unsigned short h2hi[64*128];   // 16 KB
  __shared__ unsigned short h2lo[64*128];   // 16 KB
  int t = threadIdx.x, w = t >> 6, l = t & 63;
  int m0 = blockIdx.x * 64;
  int lr = l & 15, lk = (l >> 4) * 8;       // frag row-in-tile / k elem offset

  // ---- layer 1: M=64, N=256 (wave owns 4 n-tiles), K=32 (padded 13) ----
  {
    bf16x8 axh[4], axl[4];
    #pragma unroll
    for(int mt = 0; mt < 4; mt++){
      size_t ro = (size_t)(m0 + mt*16 + lr) * 32 + lk;
      axh[mt] = *(const bf16x8*)(xphi + ro);
      axl[mt] = *(const bf16x8*)(xplo + ro);
    }
    #pragma unroll
    for(int nt = 0; nt < 4; nt++){
      int n = (w*4 + nt)*16 + lr;
      bf16x8 bw = *(const bf16x8*)(W1t + (size_t)n*32 + lk);
      f32x4 acc[4];
      #pragma unroll
      for(int mt = 0; mt < 4; mt++){
        #pragma unroll
        for(int e = 0; e < 4; e++) acc[mt][e] = 0.f;
        acc[mt] = __builtin_amdgcn_mfma_f32_16x16x32_bf16(axh[mt], bw, acc[mt], 0, 0, 0);
        acc[mt] = __builtin_amdgcn_mfma_f32_16x16x32_bf16(axl[mt], bw, acc[mt], 0, 0, 0);
      }
      float sc = g1[n]*BN_INVF, bo = be1[n], bi = b1[n];
      #pragma unroll
      for(int mt = 0; mt < 4; mt++){
        #pragma unroll
        for(int q = 0; q < 4; q++){
          int row = mt*16 + (l >> 4)*4 + q;
          float y = fmaxf(sc*(acc[mt][q] + bi) + bo, 0.f);
          uint32_t hb = f2bf(y);
          int idx = row*256 + (n ^ rswz(row));
          h1hi[idx] = (unsigned short)hb;
          h1lo[idx] = (unsigned short)f2bf(y - bf2f(hb));
        }
      }
    }
  }
  __syncthreads();

  // ---- layer 2: M=64, N=128 (wave owns 2 n-tiles), K=256 ----
  {
    f32x4 acc[4][2];
    #pragma unroll
    for(int mt = 0; mt < 4; mt++)
      #pragma unroll
      for(int nt = 0; nt < 2; nt++)
        #pragma unroll
        for(int e = 0; e < 4; e++) acc[mt][nt][e] = 0.f;
    for(int ks = 0; ks < 8; ks++){
      bf16x8 bw[2];
      #pragma unroll
      for(int nt = 0; nt < 2; nt++){
        int n = (w*2 + nt)*16 + lr;
        bw[nt] = *(const bf16x8*)(W2t + (size_t)n*256 + ks*32 + lk);
      }
      #pragma unroll
      for(int mt = 0; mt < 4; mt++){
        int row = mt*16 + lr;
        int idx = row*256 + ((ks*32 + lk) ^ rswz(row));
        bf16x8 ah = *(const bf16x8*)(h1hi + idx);
        bf16x8 al = *(const bf16x8*)(h1lo + idx);
        #pragma unroll
        for(int nt = 0; nt < 2; nt++){
          acc[mt][nt] = __builtin_amdgcn_mfma_f32_16x16x32_bf16(ah, bw[nt], acc[mt][nt], 0, 0, 0);
          acc[mt][nt] = __builtin_amdgcn_mfma_f32_16x16x32_bf16(al, bw[nt], acc[mt][nt], 0, 0, 0);
        }
      }
    }
    #pragma unroll
    for(int nt = 0; nt < 2; nt++){
      int n = (w*2 + nt)*16 + lr;
      float sc = g2[n]*BN_INVF, bo = be2[n], bi = b2[n];
      #pragma unroll
      for(int mt = 0; mt < 4; mt++){
        #pragma unroll
        for(int q = 0; q < 4; q++){
          int row = mt*16 + (l >> 4)*4 + q;
          float y = fmaxf(sc*(acc[mt][nt][q] + bi) + bo, 0.f);
          uint32_t hb = f2bf(y);
          int idx = row*128 + (n ^ rswz(row));
          h2hi[idx] = (unsigned short)hb;
          h2lo[idx] = (unsigned short)f2bf(y - bf2f(hb));
        }
      }
    }
  }
  __syncthreads();

  // ---- layer 3: M=64, N=64 (wave owns 1 n-tile), K=128, no BN/ReLU ----
  {
    f32x4 acc[4];
    #pragma unroll
    for(int mt = 0; mt < 4; mt++)
      #pragma unroll
      for(int e = 0; e < 4; e++) acc[mt][e] = 0.f;
    int n = w*16 + lr;
    for(int ks = 0; ks < 4; ks++){
      bf16x8 bw = *(const bf16x8*)(W3t + (size_t)n*128 + ks*32 + lk);
      #pragma unroll
      for(int mt = 0; mt < 4; mt++){
        int row = mt*16 + lr;
        int idx = row*128 + ((ks*32 + lk) ^ rswz(row));
        bf16x8 ah = *(const bf16x8*)(h2hi + idx);
        bf16x8 al = *(const bf16x8*)(h2lo + idx);
        acc[mt] = __builtin_amdgcn_mfma_f32_16x16x32_bf16(ah, bw, acc[mt], 0, 0, 0);
        acc[mt] = __builtin_amdgcn_mfma_f32_16x16x32_bf16(al, bw, acc[mt], 0, 0, 0);
      }
    }
    float bi = b3[n];
    #pragma unroll
    for(int mt = 0; mt < 4; mt++){
      #pragma unroll
      for(int q = 0; q < 4; q++){
        int row = m0 + mt*16 + (l >> 4)*4 + q;
        bottomBF[(size_t)row*64 + n] = (unsigned short)f2bf(acc[mt][q] + bi);
      }
    }
  }
}

// ---------------- interact: gather + Z=E·E^T (one wave per sample) --------------
// top_in layout per row (KP4=2080 bf16): [ all_emb flat 0..1727 | inter 1728..2078 | pad 2079=0 ]
__global__ __launch_bounds__(256) void interact(
    const unsigned short* __restrict__ bottomBF, const int* __restrict__ cat_idx,
    const float* __restrict__ emb, unsigned short* __restrict__ top_in){
  __shared__ unsigned short inter_s[4][352];
  int w = threadIdx.x >> 6, l = threadIdx.x & 63;
  int b = blockIdx.x * 4 + w;
  int r = l & 31, h = l >> 5;   // r = row/col of E, h = k-half
  bool active = (r < NEMB);
  uint4v q[4];
  if(active && r == 0){
    const unsigned short* sb = bottomBF + (size_t)b * 64;
    #pragma unroll
    for(int s = 0; s < 4; s++) q[s] = *(const uint4v*)(sb + h*8 + s*16);
  } else if(active){
    int f = r - 1;
    int idx = cat_idx[b * NFEAT + f];
    const float* src = emb + ((size_t)f * VROWS + (size_t)idx) * 64;
    #pragma unroll
    for(int s = 0; s < 4; s++){
      int k0 = h*8 + s*16;
      float4 v0 = *(const float4*)(src + k0);
      float4 v1 = *(const float4*)(src + k0 + 4);
      q[s][0] = pack2(v0.x, v0.y); q[s][1] = pack2(v0.z, v0.w);
      q[s][2] = pack2(v1.x, v1.y); q[s][3] = pack2(v1.z, v1.w);
    }
  } else {
    #pragma unroll
    for(int s = 0; s < 4; s++){ q[s][0]=0; q[s][1]=0; q[s][2]=0; q[s][3]=0; }
  }
  if(active){
    #pragma unroll
    for(int s = 0; s < 4; s++)
      *(uint4v*)(top_in + (size_t)b*KP4 + r*64 + h*8 + s*16) = q[s];
  }
  f32x16 acc;
  #pragma unroll
  for(int i = 0; i < 16; i++) acc[i] = 0.f;
  #pragma unroll
  for(int s = 0; s < 4; s++){
    bf16x8 a = __builtin_bit_cast(bf16x8, q[s]);
    acc = __builtin_amdgcn_mfma_f32_32x32x16_bf16(a, a, acc, 0, 0, 0);
  }
  if(active){
    #pragma unroll
    for(int qq = 0; qq < 16; qq++){
      int i = (qq & 3) + 8*(qq >> 2) + 4*h;
      if(i < r){
        int p = i*(53 - i)/2 + (r - i - 1);
        inter_s[w][p] = (unsigned short)f2bf(acc[qq]);
      }
    }
  }
  __syncthreads();
  size_t basei = (size_t)b*KP4 + 1728;
  for(int t0 = l; t0 < 176; t0 += 64){
    uint32_t lo = inter_s[w][2*t0];
    uint32_t hi = (2*t0 + 1 < NINTER) ? (uint32_t)inter_s[w][2*t0 + 1] : 0u;
    *(uint32_t*)(top_in + basei + 2*t0) = lo | (hi << 16);
  }
}

// ---------------- MFMA GEMM (m97 structure) + XCD-bijective swizzle -----------
template<int KSTEPS, int NB, bool FUSE>
__global__ __launch_bounds__(256) void gemm_top(
    const unsigned short* __restrict__ A, int sA,
    const unsigned short* __restrict__ Bw, int sB,
    const float* __restrict__ bias, const float* __restrict__ gg,
    const float* __restrict__ be,
    unsigned short* __restrict__ out, int sOut,
    const float* __restrict__ W7, const float* __restrict__ b7,
    float* __restrict__ scores){
  __shared__ unsigned short As[128*32];
  __shared__ unsigned short Bs[128*32];
  __shared__ float h6s[FUSE ? 128*132 : 1];
  __shared__ float w7s[FUSE ? 128 : 1];
  int nwg = gridDim.x;
  int bid = blockIdx.x;
  int lin = (bid & 7) * (nwg >> 3) + (bid >> 3);   // XCD chunking (nwg % 8 == 0)
  int m0 = (lin / NB) * 128, n0 = (lin % NB) * 128;
  int t = threadIdx.x, w = t >> 6, l = t & 63;
  int wr = (w >> 1) * 64, wc = (w & 1) * 64;
  f32x4 acc[4][4];
  #pragma unroll
  for(int i = 0; i < 4; i++)
    #pragma unroll
    for(int j = 0; j < 4; j++)
      #pragma unroll
      for(int e = 0; e < 4; e++) acc[i][j][e] = 0.f;

  int off0 = w*2048 + l*16;
  int row0 = off0 >> 6, ce0 = (off0 & 63) >> 1;
  int off1 = off0 + 1024;
  int row1 = off1 >> 6, ce1 = (off1 & 63) >> 1;
  const unsigned short* gA0 = A  + (size_t)(m0 + row0)*sA + ce0;
  const unsigned short* gA1 = A  + (size_t)(m0 + row1)*sA + ce1;
  const unsigned short* gB0 = Bw + (size_t)(n0 + row0)*sB + ce0;
  const unsigned short* gB1 = Bw + (size_t)(n0 + row1)*sB + ce1;
  char* ldsA0 = (char*)As + w*2048;
  char* ldsA1 = (char*)As + w*2048 + 1024;
  char* ldsB0 = (char*)Bs + w*2048;
  char* ldsB1 = (char*)Bs + w*2048 + 1024;
  int lr = l & 15;
  int lkb = (l >> 4) * 16;

  for(int kt = 0; kt < KSTEPS; kt++){
    async_load16(gA0 + kt*32, ldsA0);
    async_load16(gA1 + kt*32, ldsA1);
    async_load16(gB0 + kt*32, ldsB0);
    async_load16(gB1 + kt*32, ldsB1);
    __syncthreads();
    bf16x8 af[4], bfr[4];
    #pragma unroll
    for(int x = 0; x < 4; x++){
      af[x]  = *(const bf16x8*)((const char*)As + (wr + x*16 + lr)*64 + lkb);
      bfr[x] = *(const bf16x8*)((const char*)Bs + (wc + x*16 + lr)*64 + lkb);
    }
    #pragma unroll
    for(int tr = 0; tr < 4; tr++)
      #pragma unroll
      for(int tc = 0; tc < 4; tc++)
        acc[tr][tc] = __builtin_amdgcn_mfma_f32_16x16x32_bf16(af[tr], bfr[tc], acc[tr][tc], 0, 0, 0);
    __syncthreads();
  }

  if constexpr(!FUSE){
    #pragma unroll
    for(int tc = 0; tc < 4; tc++){
      int n = n0 + wc + tc*16 + lr;
      float sc = gg[n]*BN_INVF, bo = be[n], bi = bias[n];
      #pragma unroll
      for(int tr = 0; tr < 4; tr++){
        int mb = m0 + wr + tr*16 + (l >> 4)*4;
        #pragma unroll
        for(int qq = 0; qq < 4; qq++){
          float y = fmaxf(sc*(acc[tr][tc][qq] + bi) + bo, 0.f);
          out[(size_t)(mb + qq)*sOut + n] = (unsigned short)f2bf(y);
        }
      }
    }
  } else {
    if(t < 128) w7s[t] = W7[t];
    #pragma unroll
    for(int tc = 0; tc < 4; tc++){
      int n = wc + tc*16 + lr;
      float sc = gg[n0+n]*BN_INVF, bo = be[n0+n], bi = bias[n0+n];
      #pragma unroll
      for(int tr = 0; tr < 4; tr++){
        int mb = wr + tr*16 + (l >> 4)*4;
        #pragma unroll
        for(int qq = 0; qq < 4; qq++)
          h6s[(mb + qq)*132 + n] = fmaxf(sc*(acc[tr][tc][qq] + bi) + bo, 0.f);
      }
    }
    __syncthreads();
    if(t < 128){
      float a7 = b7[0];
      #pragma unroll 8
      for(int c = 0; c < 128; c++) a7 = fmaf(h6s[t*132 + c], w7s[c], a7);
      scores[m0 + t] = a7;
    }
  }
}

// ---------------- launch ----------------
static inline size_t alignup(size_t x){ return (x + 255) & ~(size_t)255; }

extern "C" void kernel_launch(void* const* d_in, const int* in_sizes, int n_in,
                              void* d_out, int out_size, void* d_ws, size_t ws_size,
                              hipStream_t stream){
  const float* cont = (const float*)d_in[0];
  const int*   cat  = (const int*)  d_in[1];
  const float* emb  = (const float*)d_in[2];
  const float* W1 = (const float*)d_in[3],  *b1 = (const float*)d_in[4];
  const float* g1 = (const float*)d_in[5],  *be1= (const float*)d_in[6];
  const float* W2 = (const float*)d_in[7],  *b2 = (const float*)d_in[8];
  const float* g2 = (const float*)d_in[9],  *be2= (const float*)d_in[10];
  const float* W3 = (const float*)d_in[11], *b3 = (const float*)d_in[12];
  const float* W4 = (const float*)d_in[13], *b4 = (const float*)d_in[14];
  const float* g4 = (const float*)d_in[15], *be4= (const float*)d_in[16];
  const float* W5 = (const float*)d_in[17], *b5 = (const float*)d_in[18];
  const float* g5 = (const float*)d_in[19], *be5= (const float*)d_in[20];
  const float* W6 = (const float*)d_in[21], *b6 = (const float*)d_in[22];
  const float* g6 = (const float*)d_in[23], *be6= (const float*)d_in[24];
  const float* W7 = (const float*)d_in[25], *b7 = (const float*)d_in[26];

  char* ws = (char*)d_ws;
  unsigned short* bottomBF = (unsigned short*)ws; ws += alignup((size_t)BATCH*64*2);
  unsigned short* xphi = (unsigned short*)ws; ws += alignup((size_t)BATCH*32*2);
  unsigned short* xplo = (unsigned short*)ws; ws += alignup((size_t)BATCH*32*2);
  unsigned short* W1t  = (unsigned short*)ws; ws += alignup((size_t)256*32*2);
  unsigned short* W2t  = (unsigned short*)ws; ws += alignup((size_t)128*256*2);
  unsigned short* W3t  = (unsigned short*)ws; ws += alignup((size_t)64*128*2);
  unsigned short* topi = (unsigned short*)ws; ws += alignup((size_t)BATCH*KP4*2);
  unsigned short* W4t  = (unsigned short*)ws; ws += alignup((size_t)512*KP4*2);
  unsigned short* W5t  = (unsigned short*)ws; ws += alignup((size_t)256*512*2);
  unsigned short* W6t  = (unsigned short*)ws; ws += alignup((size_t)128*256*2);
  unsigned short* h4   = (unsigned short*)ws; ws += alignup((size_t)BATCH*512*2);
  unsigned short* h5   = (unsigned short*)ws; ws += alignup((size_t)BATCH*256*2);
  (void)ws_size; (void)n_in; (void)in_sizes; (void)out_size;

  hipLaunchKernelGGL(prep, dim3(382), dim3(256), 0, stream,
                     cont, W1, W2, W3, W4, W5, W6,
                     xphi, xplo, W1t, W2t, W3t, W4t, W5t, W6t);
  hipLaunchKernelGGL(bottom_mfma, dim3(BATCH/64), dim3(256), 0, stream,
                     xphi, xplo, W1t, W2t, W3t,
                     b1, g1, be1, b2, g2, be2, b3, bottomBF);
  hipLaunchKernelGGL(interact, dim3(BATCH/4), dim3(256), 0, stream, bottomBF, cat, emb, topi);
  hipLaunchKernelGGL((gemm_top<KP4/32, 4, false>), dim3(512), dim3(256), 0, stream,
                     topi, KP4, W4t, KP4, b4, g4, be4, h4, 512,
                     (const float*)nullptr, (const float*)nullptr, (float*)nullptr);
  hipLaunchKernelGGL((gemm_top<16, 2, false>), dim3(256), dim3(256), 0, stream,
                     h4, 512, W5t, 512, b5, g5, be5, h5, 256,
                     (const float*)nullptr, (const float*)nullptr, (float*)nullptr);
  hipLaunchKernelGGL((gemm_top<8, 1, true>), dim3(128), dim3(256), 0, stream,
                     h5, 256, W6t, 256, b6, g6, be6, (unsigned short*)nullptr, 0,
                     W7, b7, (float*)d_out);
}

// Round 3
// 125.170 us; speedup vs baseline: 1.6002x; 1.1624x over previous
//
#include <hip/hip_runtime.h>
#include <stdint.h>
#include <stddef.h>

// ---------------- constants ----------------
#define BATCH   16384
#define CDIM    13
#define NFEAT   26
#define VROWS   100000
#define EDIM    64
#define NEMB    27      // bottom + 26 embeddings
#define NINTER  351     // 27*26/2
#define TOPIN   2079    // 351 + 27*64
#define KP4     2112    // padded K for layer 4 (33 x 64)
#define BN_INVF 0.9999950000374997f

typedef __attribute__((ext_vector_type(8)))  __bf16 bf16x8;
typedef __attribute__((ext_vector_type(4)))  float  f32x4;
typedef __attribute__((ext_vector_type(16))) float  f32x16;
typedef __attribute__((ext_vector_type(4)))  uint32_t uint4v;

__device__ __forceinline__ uint32_t f2bf(float f){
  uint32_t u = __float_as_uint(f);
  return (u + 0x7fffu + ((u >> 16) & 1u)) >> 16;   // RNE
}
__device__ __forceinline__ float bf2f(uint32_t h){ return __uint_as_float(h << 16); }
__device__ __forceinline__ uint32_t pack2(float a, float b){
  return f2bf(a) | (f2bf(b) << 16);
}
__device__ __forceinline__ void async_load16(const void* g, void* l){
  __builtin_amdgcn_global_load_lds(
      (const __attribute__((address_space(1))) uint32_t*)g,
      (__attribute__((address_space(3))) uint32_t*)l, 16, 0, 0);
}
// activation-LDS row swizzle for bottom_mfma
__device__ __forceinline__ int rswz(int row){ return ((row ^ (row >> 3)) & 7) << 3; }

// ---------------- prep: all weight transposes + x hi/lo split (one launch) ----
__device__ __forceinline__ void transpose_tile(
    float (*tile)[65], const float* __restrict__ src, unsigned short* __restrict__ dst,
    int K, int N, int Kpad, int remap, int kb, int nb){
  int k0 = kb*64, n0 = nb*64, t = threadIdx.x;
  int srcBase = remap ? ((k0 < 1728) ? (k0 + 351) : (k0 - 1728)) : k0;
  #pragma unroll 4
  for(int p = 0; p < 16; p++){
    int kr = p*4 + (t >> 6), nc = t & 63;
    float v = 0.f;
    if(k0 + kr < K && (n0 + nc) < N) v = src[(size_t)(srcBase + kr) * N + n0 + nc];
    tile[kr][nc] = v;
  }
  __syncthreads();
  #pragma unroll 4
  for(int p = 0; p < 16; p++){
    int nr = p*4 + (t >> 6), kc = t & 63;
    if(k0 + kc < Kpad && (n0 + nr) < N)
      dst[(size_t)(n0 + nr) * Kpad + k0 + kc] = (unsigned short)f2bf(tile[kc][nr]);
  }
}

__global__ __launch_bounds__(256) void prep(
    const float* __restrict__ cont,
    const float* __restrict__ W1, const float* __restrict__ W2, const float* __restrict__ W3,
    const float* __restrict__ W4, const float* __restrict__ W5, const float* __restrict__ W6,
    unsigned short* __restrict__ xphi, unsigned short* __restrict__ xplo,
    unsigned short* __restrict__ W1t, unsigned short* __restrict__ W2t,
    unsigned short* __restrict__ W3t, unsigned short* __restrict__ W4t,
    unsigned short* __restrict__ W5t, unsigned short* __restrict__ W6t){
  __shared__ float tile[64][65];
  int bid = blockIdx.x;
  if(bid < 264){ transpose_tile(tile, W4, W4t, TOPIN, 512, KP4, 1, bid % 33, bid / 33); }
  else if(bid < 296){ int r = bid-264; transpose_tile(tile, W5, W5t, 512, 256, 512, 0, r % 8, r / 8); }
  else if(bid < 304){ int r = bid-296; transpose_tile(tile, W6, W6t, 256, 128, 256, 0, r % 4, r / 4); }
  else if(bid < 312){ int r = bid-304; transpose_tile(tile, W2, W2t, 256, 128, 256, 0, r % 4, r / 4); }
  else if(bid < 314){ int r = bid-312; transpose_tile(tile, W3, W3t, 128, 64, 128, 0, r, 0); }
  else if(bid < 318){ int r = bid-314; transpose_tile(tile, W1, W1t, CDIM, 256, 32, 0, 0, r); }
  else {
    // x -> hi/lo bf16, padded 13 -> 32
    int row = (bid - 318) * 256 + threadIdx.x;
    const float* xr = cont + (size_t)row * CDIM;
    uint32_t uh[16], ul[16];
    #pragma unroll
    for(int k = 0; k < 16; k++){
      uint32_t h0=0, h1=0, l0=0, l1=0;
      if(2*k < CDIM){
        float x = xr[2*k]; h0 = f2bf(x); l0 = f2bf(x - bf2f(h0));
      }
      if(2*k+1 < CDIM){
        float x = xr[2*k+1]; h1 = f2bf(x); l1 = f2bf(x - bf2f(h1));
      }
      uh[k] = h0 | (h1 << 16);
      ul[k] = l0 | (l1 << 16);
    }
    #pragma unroll
    for(int s = 0; s < 4; s++){
      uint4v vh, vl;
      #pragma unroll
      for(int e = 0; e < 4; e++){ vh[e] = uh[4*s+e]; vl[e] = ul[4*s+e]; }
      *(uint4v*)(xphi + (size_t)row*32 + s*8) = vh;
      *(uint4v*)(xplo + (size_t)row*32 + s*8) = vl;
    }
  }
}

// ---------------- bottom MLP via MFMA, hi/lo-compensated activations ----------
__global__ __launch_bounds__(256) void bottom_mfma(
    const unsigned short* __restrict__ xphi, const unsigned short* __restrict__ xplo,
    const unsigned short* __restrict__ W1t, const unsigned short* __restrict__ W2t,
    const unsigned short* __restrict__ W3t,
    const float* __restrict__ b1, const float* __restrict__ g1, const float* __restrict__ be1,
    const float* __restrict__ b2, const float* __restrict__ g2, const float* __restrict__ be2,
    const float* __restrict__ b3,
    unsigned short* __restrict__ bottomBF){
  __shared__ unsigned short h1hi[64*256];
  __shared__ unsigned short h1lo[64*256];
  __shared__ unsigned short h2hi[64*128];
  __shared__ unsigned short h2lo[64*128];
  int t = threadIdx.x, w = t >> 6, l = t & 63;
  int m0 = blockIdx.x * 64;
  int lr = l & 15, lk = (l >> 4) * 8;

  { // layer 1: M=64, N=256, K=32
    bf16x8 axh[4], axl[4];
    #pragma unroll
    for(int mt = 0; mt < 4; mt++){
      size_t ro = (size_t)(m0 + mt*16 + lr) * 32 + lk;
      axh[mt] = *(const bf16x8*)(xphi + ro);
      axl[mt] = *(const bf16x8*)(xplo + ro);
    }
    #pragma unroll
    for(int nt = 0; nt < 4; nt++){
      int n = (w*4 + nt)*16 + lr;
      bf16x8 bw = *(const bf16x8*)(W1t + (size_t)n*32 + lk);
      f32x4 acc[4];
      #pragma unroll
      for(int mt = 0; mt < 4; mt++){
        #pragma unroll
        for(int e = 0; e < 4; e++) acc[mt][e] = 0.f;
        acc[mt] = __builtin_amdgcn_mfma_f32_16x16x32_bf16(axh[mt], bw, acc[mt], 0, 0, 0);
        acc[mt] = __builtin_amdgcn_mfma_f32_16x16x32_bf16(axl[mt], bw, acc[mt], 0, 0, 0);
      }
      float sc = g1[n]*BN_INVF, bo = be1[n], bi = b1[n];
      #pragma unroll
      for(int mt = 0; mt < 4; mt++){
        #pragma unroll
        for(int q = 0; q < 4; q++){
          int row = mt*16 + (l >> 4)*4 + q;
          float y = fmaxf(sc*(acc[mt][q] + bi) + bo, 0.f);
          uint32_t hb = f2bf(y);
          int idx = row*256 + (n ^ rswz(row));
          h1hi[idx] = (unsigned short)hb;
          h1lo[idx] = (unsigned short)f2bf(y - bf2f(hb));
        }
      }
    }
  }
  __syncthreads();

  { // layer 2: M=64, N=128, K=256
    f32x4 acc[4][2];
    #pragma unroll
    for(int mt = 0; mt < 4; mt++)
      #pragma unroll
      for(int nt = 0; nt < 2; nt++)
        #pragma unroll
        for(int e = 0; e < 4; e++) acc[mt][nt][e] = 0.f;
    for(int ks = 0; ks < 8; ks++){
      bf16x8 bw[2];
      #pragma unroll
      for(int nt = 0; nt < 2; nt++){
        int n = (w*2 + nt)*16 + lr;
        bw[nt] = *(const bf16x8*)(W2t + (size_t)n*256 + ks*32 + lk);
      }
      #pragma unroll
      for(int mt = 0; mt < 4; mt++){
        int row = mt*16 + lr;
        int idx = row*256 + ((ks*32 + lk) ^ rswz(row));
        bf16x8 ah = *(const bf16x8*)(h1hi + idx);
        bf16x8 al = *(const bf16x8*)(h1lo + idx);
        #pragma unroll
        for(int nt = 0; nt < 2; nt++){
          acc[mt][nt] = __builtin_amdgcn_mfma_f32_16x16x32_bf16(ah, bw[nt], acc[mt][nt], 0, 0, 0);
          acc[mt][nt] = __builtin_amdgcn_mfma_f32_16x16x32_bf16(al, bw[nt], acc[mt][nt], 0, 0, 0);
        }
      }
    }
    #pragma unroll
    for(int nt = 0; nt < 2; nt++){
      int n = (w*2 + nt)*16 + lr;
      float sc = g2[n]*BN_INVF, bo = be2[n], bi = b2[n];
      #pragma unroll
      for(int mt = 0; mt < 4; mt++){
        #pragma unroll
        for(int q = 0; q < 4; q++){
          int row = mt*16 + (l >> 4)*4 + q;
          float y = fmaxf(sc*(acc[mt][nt][q] + bi) + bo, 0.f);
          uint32_t hb = f2bf(y);
          int idx = row*128 + (n ^ rswz(row));
          h2hi[idx] = (unsigned short)hb;
          h2lo[idx] = (unsigned short)f2bf(y - bf2f(hb));
        }
      }
    }
  }
  __syncthreads();

  { // layer 3: M=64, N=64, K=128, no BN/ReLU
    f32x4 acc[4];
    #pragma unroll
    for(int mt = 0; mt < 4; mt++)
      #pragma unroll
      for(int e = 0; e < 4; e++) acc[mt][e] = 0.f;
    int n = w*16 + lr;
    for(int ks = 0; ks < 4; ks++){
      bf16x8 bw = *(const bf16x8*)(W3t + (size_t)n*128 + ks*32 + lk);
      #pragma unroll
      for(int mt = 0; mt < 4; mt++){
        int row = mt*16 + lr;
        int idx = row*128 + ((ks*32 + lk) ^ rswz(row));
        bf16x8 ah = *(const bf16x8*)(h2hi + idx);
        bf16x8 al = *(const bf16x8*)(h2lo + idx);
        acc[mt] = __builtin_amdgcn_mfma_f32_16x16x32_bf16(ah, bw, acc[mt], 0, 0, 0);
        acc[mt] = __builtin_amdgcn_mfma_f32_16x16x32_bf16(al, bw, acc[mt], 0, 0, 0);
      }
    }
    float bi = b3[n];
    #pragma unroll
    for(int mt = 0; mt < 4; mt++){
      #pragma unroll
      for(int q = 0; q < 4; q++){
        int row = m0 + mt*16 + (l >> 4)*4 + q;
        bottomBF[(size_t)row*64 + n] = (unsigned short)f2bf(acc[mt][q] + bi);
      }
    }
  }
}

// ---------------- interact: gather + Z=E·E^T (one wave per sample) --------------
// top_in row (KP4=2112): [ all_emb 0..1727 | inter 1728..2078 | pad 2079..2111 = 0 ]
__global__ __launch_bounds__(256) void interact(
    const unsigned short* __restrict__ bottomBF, const int* __restrict__ cat_idx,
    const float* __restrict__ emb, unsigned short* __restrict__ top_in){
  __shared__ unsigned short inter_s[4][352];
  int w = threadIdx.x >> 6, l = threadIdx.x & 63;
  int b = blockIdx.x * 4 + w;
  int r = l & 31, h = l >> 5;
  bool active = (r < NEMB);
  uint4v q[4];
  if(active && r == 0){
    const unsigned short* sb = bottomBF + (size_t)b * 64;
    #pragma unroll
    for(int s = 0; s < 4; s++) q[s] = *(const uint4v*)(sb + h*8 + s*16);
  } else if(active){
    int f = r - 1;
    int idx = cat_idx[b * NFEAT + f];
    const float* src = emb + ((size_t)f * VROWS + (size_t)idx) * 64;
    #pragma unroll
    for(int s = 0; s < 4; s++){
      int k0 = h*8 + s*16;
      float4 v0 = *(const float4*)(src + k0);
      float4 v1 = *(const float4*)(src + k0 + 4);
      q[s][0] = pack2(v0.x, v0.y); q[s][1] = pack2(v0.z, v0.w);
      q[s][2] = pack2(v1.x, v1.y); q[s][3] = pack2(v1.z, v1.w);
    }
  } else {
    #pragma unroll
    for(int s = 0; s < 4; s++){ q[s][0]=0; q[s][1]=0; q[s][2]=0; q[s][3]=0; }
  }
  if(active){
    #pragma unroll
    for(int s = 0; s < 4; s++)
      *(uint4v*)(top_in + (size_t)b*KP4 + r*64 + h*8 + s*16) = q[s];
  }
  f32x16 acc;
  #pragma unroll
  for(int i = 0; i < 16; i++) acc[i] = 0.f;
  #pragma unroll
  for(int s = 0; s < 4; s++){
    bf16x8 a = __builtin_bit_cast(bf16x8, q[s]);
    acc = __builtin_amdgcn_mfma_f32_32x32x16_bf16(a, a, acc, 0, 0, 0);
  }
  if(active){
    #pragma unroll
    for(int qq = 0; qq < 16; qq++){
      int i = (qq & 3) + 8*(qq >> 2) + 4*h;
      if(i < r){
        int p = i*(53 - i)/2 + (r - i - 1);
        inter_s[w][p] = (unsigned short)f2bf(acc[qq]);
      }
    }
  }
  __syncthreads();
  size_t basei = (size_t)b*KP4 + 1728;
  for(int t0 = l; t0 < 176; t0 += 64){
    uint32_t lo = inter_s[w][2*t0];
    uint32_t hi = (2*t0 + 1 < NINTER) ? (uint32_t)inter_s[w][2*t0 + 1] : 0u;
    *(uint32_t*)(top_in + basei + 2*t0) = lo | (hi << 16);
  }
  // zero pad cols 2080..2111
  if(l < 16) *(uint32_t*)(top_in + (size_t)b*KP4 + 2080 + 2*l) = 0;
}

// ---------------- MFMA GEMM: BK=64, both-sides XOR swizzle, XCD-chunked -------
// LDS rows = 128B (64 bf16); swizzle: byte ^= ((row&7)<<4) applied to global src
// (inverse) and ds_read addr; LDS dest of global_load_lds stays linear.
template<int KSTEPS, int NB, bool FUSE>
__global__ __launch_bounds__(256) void gemm_top(
    const unsigned short* __restrict__ A, int sA,
    const unsigned short* __restrict__ Bw, int sB,
    const float* __restrict__ bias, const float* __restrict__ gg,
    const float* __restrict__ be,
    unsigned short* __restrict__ out, int sOut,
    const float* __restrict__ W7, const float* __restrict__ b7,
    float* __restrict__ scores){
  __shared__ unsigned short As[128*64];
  __shared__ unsigned short Bs[128*64];
  __shared__ float h6s[FUSE ? 128*132 : 1];
  __shared__ float w7s[FUSE ? 128 : 1];
  int nwg = gridDim.x;
  int bid = blockIdx.x;
  int lin = (bid & 7) * (nwg >> 3) + (bid >> 3);   // XCD chunking (nwg % 8 == 0)
  int m0 = (lin / NB) * 128, n0 = (lin % NB) * 128;
  int t = threadIdx.x, w = t >> 6, l = t & 63;
  int wr = (w >> 1) * 64, wc = (w & 1) * 64;
  f32x4 acc[4][4];
  #pragma unroll
  for(int i = 0; i < 4; i++)
    #pragma unroll
    for(int j = 0; j < 4; j++)
      #pragma unroll
      for(int e = 0; e < 4; e++) acc[i][j][e] = 0.f;

  // staging: 4 issues of 16B per matrix per thread; dest linear, src pre-swizzled
  const unsigned short* gA[4];
  const unsigned short* gB[4];
  char* ldsA[4];
  char* ldsB[4];
  #pragma unroll
  for(int i = 0; i < 4; i++){
    int o   = w*4096 + i*1024 + l*16;       // byte offset in 16KB tile
    int row = o >> 7;
    int cb  = (o & 127) ^ ((row & 7) << 4); // inverse swizzle on source
    gA[i] = A  + (size_t)(m0 + row)*sA + (cb >> 1);
    gB[i] = Bw + (size_t)(n0 + row)*sB + (cb >> 1);
    ldsA[i] = (char*)As + o;
    ldsB[i] = (char*)Bs + o;
  }
  int lr = l & 15;
  int rs = (l & 7) << 4;                    // read-side swizzle const
  int o1 = ((l >> 4) * 16) ^ rs;            // k-chunk byte offset, ks=0
  // ks=1 offset = o1 ^ 64

  for(int kt = 0; kt < KSTEPS; kt++){
    #pragma unroll
    for(int i = 0; i < 4; i++){
      async_load16(gA[i] + kt*64, ldsA[i]);
      async_load16(gB[i] + kt*64, ldsB[i]);
    }
    __syncthreads();
    #pragma unroll
    for(int ks = 0; ks < 2; ks++){
      int ko = o1 ^ (ks << 6);
      bf16x8 af[4], bfr[4];
      #pragma unroll
      for(int x = 0; x < 4; x++){
        af[x]  = *(const bf16x8*)((const char*)As + (wr + x*16 + lr)*128 + ko);
        bfr[x] = *(const bf16x8*)((const char*)Bs + (wc + x*16 + lr)*128 + ko);
      }
      #pragma unroll
      for(int tr = 0; tr < 4; tr++)
        #pragma unroll
        for(int tc = 0; tc < 4; tc++)
          acc[tr][tc] = __builtin_amdgcn_mfma_f32_16x16x32_bf16(af[tr], bfr[tc], acc[tr][tc], 0, 0, 0);
    }
    __syncthreads();
  }

  if constexpr(!FUSE){
    #pragma unroll
    for(int tc = 0; tc < 4; tc++){
      int n = n0 + wc + tc*16 + lr;
      float sc = gg[n]*BN_INVF, bo = be[n], bi = bias[n];
      #pragma unroll
      for(int tr = 0; tr < 4; tr++){
        int mb = m0 + wr + tr*16 + (l >> 4)*4;
        #pragma unroll
        for(int qq = 0; qq < 4; qq++){
          float y = fmaxf(sc*(acc[tr][tc][qq] + bi) + bo, 0.f);
          out[(size_t)(mb + qq)*sOut + n] = (unsigned short)f2bf(y);
        }
      }
    }
  } else {
    if(t < 128) w7s[t] = W7[t];
    #pragma unroll
    for(int tc = 0; tc < 4; tc++){
      int n = wc + tc*16 + lr;
      float sc = gg[n0+n]*BN_INVF, bo = be[n0+n], bi = bias[n0+n];
      #pragma unroll
      for(int tr = 0; tr < 4; tr++){
        int mb = wr + tr*16 + (l >> 4)*4;
        #pragma unroll
        for(int qq = 0; qq < 4; qq++)
          h6s[(mb + qq)*132 + n] = fmaxf(sc*(acc[tr][tc][qq] + bi) + bo, 0.f);
      }
    }
    __syncthreads();
    if(t < 128){
      float a7 = b7[0];
      #pragma unroll 8
      for(int c = 0; c < 128; c++) a7 = fmaf(h6s[t*132 + c], w7s[c], a7);
      scores[m0 + t] = a7;
    }
  }
}

// ---------------- launch ----------------
static inline size_t alignup(size_t x){ return (x + 255) & ~(size_t)255; }

extern "C" void kernel_launch(void* const* d_in, const int* in_sizes, int n_in,
                              void* d_out, int out_size, void* d_ws, size_t ws_size,
                              hipStream_t stream){
  const float* cont = (const float*)d_in[0];
  const int*   cat  = (const int*)  d_in[1];
  const float* emb  = (const float*)d_in[2];
  const float* W1 = (const float*)d_in[3],  *b1 = (const float*)d_in[4];
  const float* g1 = (const float*)d_in[5],  *be1= (const float*)d_in[6];
  const float* W2 = (const float*)d_in[7],  *b2 = (const float*)d_in[8];
  const float* g2 = (const float*)d_in[9],  *be2= (const float*)d_in[10];
  const float* W3 = (const float*)d_in[11], *b3 = (const float*)d_in[12];
  const float* W4 = (const float*)d_in[13], *b4 = (const float*)d_in[14];
  const float* g4 = (const float*)d_in[15], *be4= (const float*)d_in[16];
  const float* W5 = (const float*)d_in[17], *b5 = (const float*)d_in[18];
  const float* g5 = (const float*)d_in[19], *be5= (const float*)d_in[20];
  const float* W6 = (const float*)d_in[21], *b6 = (const float*)d_in[22];
  const float* g6 = (const float*)d_in[23], *be6= (const float*)d_in[24];
  const float* W7 = (const float*)d_in[25], *b7 = (const float*)d_in[26];

  char* ws = (char*)d_ws;
  unsigned short* bottomBF = (unsigned short*)ws; ws += alignup((size_t)BATCH*64*2);
  unsigned short* xphi = (unsigned short*)ws; ws += alignup((size_t)BATCH*32*2);
  unsigned short* xplo = (unsigned short*)ws; ws += alignup((size_t)BATCH*32*2);
  unsigned short* W1t  = (unsigned short*)ws; ws += alignup((size_t)256*32*2);
  unsigned short* W2t  = (unsigned short*)ws; ws += alignup((size_t)128*256*2);
  unsigned short* W3t  = (unsigned short*)ws; ws += alignup((size_t)64*128*2);
  unsigned short* topi = (unsigned short*)ws; ws += alignup((size_t)BATCH*KP4*2);
  unsigned short* W4t  = (unsigned short*)ws; ws += alignup((size_t)512*KP4*2);
  unsigned short* W5t  = (unsigned short*)ws; ws += alignup((size_t)256*512*2);
  unsigned short* W6t  = (unsigned short*)ws; ws += alignup((size_t)128*256*2);
  unsigned short* h4   = (unsigned short*)ws; ws += alignup((size_t)BATCH*512*2);
  unsigned short* h5   = (unsigned short*)ws; ws += alignup((size_t)BATCH*256*2);
  (void)ws_size; (void)n_in; (void)in_sizes; (void)out_size;

  hipLaunchKernelGGL(prep, dim3(382), dim3(256), 0, stream,
                     cont, W1, W2, W3, W4, W5, W6,
                     xphi, xplo, W1t, W2t, W3t, W4t, W5t, W6t);
  hipLaunchKernelGGL(bottom_mfma, dim3(BATCH/64), dim3(256), 0, stream,
                     xphi, xplo, W1t, W2t, W3t,
                     b1, g1, be1, b2, g2, be2, b3, bottomBF);
  hipLaunchKernelGGL(interact, dim3(BATCH/4), dim3(256), 0, stream, bottomBF, cat, emb, topi);
  hipLaunchKernelGGL((gemm_top<33, 4, false>), dim3(512), dim3(256), 0, stream,
                     topi, KP4, W4t, KP4, b4, g4, be4, h4, 512,
                     (const float*)nullptr, (const float*)nullptr, (float*)nullptr);
  hipLaunchKernelGGL((gemm_top<8, 2, false>), dim3(256), dim3(256), 0, stream,
                     h4, 512, W5t, 512, b5, g5, be5, h5, 256,
                     (const float*)nullptr, (const float*)nullptr, (float*)nullptr);
  hipLaunchKernelGGL((gemm_top<4, 1, true>), dim3(128), dim3(256), 0, stream,
                     h5, 256, W6t, 256, b6, g6, be6, (unsigned short*)nullptr, 0,
                     W7, b7, (float*)d_out);
}

// Round 4
// 119.308 us; speedup vs baseline: 1.6788x; 1.0491x over previous
//
#include <hip/hip_runtime.h>
#include <stdint.h>
#include <stddef.h>

// ---------------- constants ----------------
#define BATCH   16384
#define CDIM    13
#define NFEAT   26
#define VROWS   100000
#define EDIM    64
#define NEMB    27      // bottom + 26 embeddings
#define NINTER  351     // 27*26/2
#define TOPIN   2079    // 351 + 27*64
#define KP4     2112    // padded K for layer 4 (33 x 64)
#define BN_INVF 0.9999950000374997f

typedef __attribute__((ext_vector_type(8)))  __bf16 bf16x8;
typedef __attribute__((ext_vector_type(4)))  float  f32x4;
typedef __attribute__((ext_vector_type(16))) float  f32x16;
typedef __attribute__((ext_vector_type(4)))  uint32_t uint4v;

__device__ __forceinline__ uint32_t f2bf(float f){
  uint32_t u = __float_as_uint(f);
  return (u + 0x7fffu + ((u >> 16) & 1u)) >> 16;   // RNE
}
__device__ __forceinline__ float bf2f(uint32_t h){ return __uint_as_float(h << 16); }
__device__ __forceinline__ uint32_t pack2(float a, float b){
  return f2bf(a) | (f2bf(b) << 16);
}
__device__ __forceinline__ void async_load16(const void* g, void* l){
  __builtin_amdgcn_global_load_lds(
      (const __attribute__((address_space(1))) uint32_t*)g,
      (__attribute__((address_space(3))) uint32_t*)l, 16, 0, 0);
}
// activation-LDS row swizzle for bottom_mfma
__device__ __forceinline__ int rswz(int row){ return ((row ^ (row >> 3)) & 7) << 3; }

// ---------------- prep: all weight transposes + x hi/lo split (one launch) ----
__device__ __forceinline__ void transpose_tile(
    float (*tile)[65], const float* __restrict__ src, unsigned short* __restrict__ dst,
    int K, int N, int Kpad, int remap, int kb, int nb){
  int k0 = kb*64, n0 = nb*64, t = threadIdx.x;
  int srcBase = remap ? ((k0 < 1728) ? (k0 + 351) : (k0 - 1728)) : k0;
  #pragma unroll 4
  for(int p = 0; p < 16; p++){
    int kr = p*4 + (t >> 6), nc = t & 63;
    float v = 0.f;
    if(k0 + kr < K && (n0 + nc) < N) v = src[(size_t)(srcBase + kr) * N + n0 + nc];
    tile[kr][nc] = v;
  }
  __syncthreads();
  #pragma unroll 4
  for(int p = 0; p < 16; p++){
    int nr = p*4 + (t >> 6), kc = t & 63;
    if(k0 + kc < Kpad && (n0 + nr) < N)
      dst[(size_t)(n0 + nr) * Kpad + k0 + kc] = (unsigned short)f2bf(tile[kc][nr]);
  }
}

__global__ __launch_bounds__(256) void prep(
    const float* __restrict__ cont,
    const float* __restrict__ W1, const float* __restrict__ W2, const float* __restrict__ W3,
    const float* __restrict__ W4, const float* __restrict__ W5, const float* __restrict__ W6,
    unsigned short* __restrict__ xphi, unsigned short* __restrict__ xplo,
    unsigned short* __restrict__ W1t, unsigned short* __restrict__ W2t,
    unsigned short* __restrict__ W3t, unsigned short* __restrict__ W4t,
    unsigned short* __restrict__ W5t, unsigned short* __restrict__ W6t){
  __shared__ float tile[64][65];
  int bid = blockIdx.x;
  if(bid < 264){ transpose_tile(tile, W4, W4t, TOPIN, 512, KP4, 1, bid % 33, bid / 33); }
  else if(bid < 296){ int r = bid-264; transpose_tile(tile, W5, W5t, 512, 256, 512, 0, r % 8, r / 8); }
  else if(bid < 304){ int r = bid-296; transpose_tile(tile, W6, W6t, 256, 128, 256, 0, r % 4, r / 4); }
  else if(bid < 312){ int r = bid-304; transpose_tile(tile, W2, W2t, 256, 128, 256, 0, r % 4, r / 4); }
  else if(bid < 314){ int r = bid-312; transpose_tile(tile, W3, W3t, 128, 64, 128, 0, r, 0); }
  else if(bid < 318){ int r = bid-314; transpose_tile(tile, W1, W1t, CDIM, 256, 32, 0, 0, r); }
  else {
    // x -> hi/lo bf16, padded 13 -> 32
    int row = (bid - 318) * 256 + threadIdx.x;
    const float* xr = cont + (size_t)row * CDIM;
    uint32_t uh[16], ul[16];
    #pragma unroll
    for(int k = 0; k < 16; k++){
      uint32_t h0=0, h1=0, l0=0, l1=0;
      if(2*k < CDIM){
        float x = xr[2*k]; h0 = f2bf(x); l0 = f2bf(x - bf2f(h0));
      }
      if(2*k+1 < CDIM){
        float x = xr[2*k+1]; h1 = f2bf(x); l1 = f2bf(x - bf2f(h1));
      }
      uh[k] = h0 | (h1 << 16);
      ul[k] = l0 | (l1 << 16);
    }
    #pragma unroll
    for(int s = 0; s < 4; s++){
      uint4v vh, vl;
      #pragma unroll
      for(int e = 0; e < 4; e++){ vh[e] = uh[4*s+e]; vl[e] = ul[4*s+e]; }
      *(uint4v*)(xphi + (size_t)row*32 + s*8) = vh;
      *(uint4v*)(xplo + (size_t)row*32 + s*8) = vl;
    }
  }
}

// ---------------- bottom MLP via MFMA, hi/lo-compensated activations ----------
__global__ __launch_bounds__(256) void bottom_mfma(
    const unsigned short* __restrict__ xphi, const unsigned short* __restrict__ xplo,
    const unsigned short* __restrict__ W1t, const unsigned short* __restrict__ W2t,
    const unsigned short* __restrict__ W3t,
    const float* __restrict__ b1, const float* __restrict__ g1, const float* __restrict__ be1,
    const float* __restrict__ b2, const float* __restrict__ g2, const float* __restrict__ be2,
    const float* __restrict__ b3,
    unsigned short* __restrict__ bottomBF){
  __shared__ unsigned short h1hi[64*256];
  __shared__ unsigned short h1lo[64*256];
  __shared__ unsigned short h2hi[64*128];
  __shared__ unsigned short h2lo[64*128];
  int t = threadIdx.x, w = t >> 6, l = t & 63;
  int m0 = blockIdx.x * 64;
  int lr = l & 15, lk = (l >> 4) * 8;

  { // layer 1: M=64, N=256, K=32
    bf16x8 axh[4], axl[4];
    #pragma unroll
    for(int mt = 0; mt < 4; mt++){
      size_t ro = (size_t)(m0 + mt*16 + lr) * 32 + lk;
      axh[mt] = *(const bf16x8*)(xphi + ro);
      axl[mt] = *(const bf16x8*)(xplo + ro);
    }
    #pragma unroll
    for(int nt = 0; nt < 4; nt++){
      int n = (w*4 + nt)*16 + lr;
      bf16x8 bw = *(const bf16x8*)(W1t + (size_t)n*32 + lk);
      f32x4 acc[4];
      #pragma unroll
      for(int mt = 0; mt < 4; mt++){
        #pragma unroll
        for(int e = 0; e < 4; e++) acc[mt][e] = 0.f;
        acc[mt] = __builtin_amdgcn_mfma_f32_16x16x32_bf16(axh[mt], bw, acc[mt], 0, 0, 0);
        acc[mt] = __builtin_amdgcn_mfma_f32_16x16x32_bf16(axl[mt], bw, acc[mt], 0, 0, 0);
      }
      float sc = g1[n]*BN_INVF, bo = be1[n], bi = b1[n];
      #pragma unroll
      for(int mt = 0; mt < 4; mt++){
        #pragma unroll
        for(int q = 0; q < 4; q++){
          int row = mt*16 + (l >> 4)*4 + q;
          float y = fmaxf(sc*(acc[mt][q] + bi) + bo, 0.f);
          uint32_t hb = f2bf(y);
          int idx = row*256 + (n ^ rswz(row));
          h1hi[idx] = (unsigned short)hb;
          h1lo[idx] = (unsigned short)f2bf(y - bf2f(hb));
        }
      }
    }
  }
  __syncthreads();

  { // layer 2: M=64, N=128, K=256
    f32x4 acc[4][2];
    #pragma unroll
    for(int mt = 0; mt < 4; mt++)
      #pragma unroll
      for(int nt = 0; nt < 2; nt++)
        #pragma unroll
        for(int e = 0; e < 4; e++) acc[mt][nt][e] = 0.f;
    for(int ks = 0; ks < 8; ks++){
      bf16x8 bw[2];
      #pragma unroll
      for(int nt = 0; nt < 2; nt++){
        int n = (w*2 + nt)*16 + lr;
        bw[nt] = *(const bf16x8*)(W2t + (size_t)n*256 + ks*32 + lk);
      }
      #pragma unroll
      for(int mt = 0; mt < 4; mt++){
        int row = mt*16 + lr;
        int idx = row*256 + ((ks*32 + lk) ^ rswz(row));
        bf16x8 ah = *(const bf16x8*)(h1hi + idx);
        bf16x8 al = *(const bf16x8*)(h1lo + idx);
        #pragma unroll
        for(int nt = 0; nt < 2; nt++){
          acc[mt][nt] = __builtin_amdgcn_mfma_f32_16x16x32_bf16(ah, bw[nt], acc[mt][nt], 0, 0, 0);
          acc[mt][nt] = __builtin_amdgcn_mfma_f32_16x16x32_bf16(al, bw[nt], acc[mt][nt], 0, 0, 0);
        }
      }
    }
    #pragma unroll
    for(int nt = 0; nt < 2; nt++){
      int n = (w*2 + nt)*16 + lr;
      float sc = g2[n]*BN_INVF, bo = be2[n], bi = b2[n];
      #pragma unroll
      for(int mt = 0; mt < 4; mt++){
        #pragma unroll
        for(int q = 0; q < 4; q++){
          int row = mt*16 + (l >> 4)*4 + q;
          float y = fmaxf(sc*(acc[mt][nt][q] + bi) + bo, 0.f);
          uint32_t hb = f2bf(y);
          int idx = row*128 + (n ^ rswz(row));
          h2hi[idx] = (unsigned short)hb;
          h2lo[idx] = (unsigned short)f2bf(y - bf2f(hb));
        }
      }
    }
  }
  __syncthreads();

  { // layer 3: M=64, N=64, K=128, no BN/ReLU
    f32x4 acc[4];
    #pragma unroll
    for(int mt = 0; mt < 4; mt++)
      #pragma unroll
      for(int e = 0; e < 4; e++) acc[mt][e] = 0.f;
    int n = w*16 + lr;
    for(int ks = 0; ks < 4; ks++){
      bf16x8 bw = *(const bf16x8*)(W3t + (size_t)n*128 + ks*32 + lk);
      #pragma unroll
      for(int mt = 0; mt < 4; mt++){
        int row = mt*16 + lr;
        int idx = row*128 + ((ks*32 + lk) ^ rswz(row));
        bf16x8 ah = *(const bf16x8*)(h2hi + idx);
        bf16x8 al = *(const bf16x8*)(h2lo + idx);
        acc[mt] = __builtin_amdgcn_mfma_f32_16x16x32_bf16(ah, bw, acc[mt], 0, 0, 0);
        acc[mt] = __builtin_amdgcn_mfma_f32_16x16x32_bf16(al, bw, acc[mt], 0, 0, 0);
      }
    }
    float bi = b3[n];
    #pragma unroll
    for(int mt = 0; mt < 4; mt++){
      #pragma unroll
      for(int q = 0; q < 4; q++){
        int row = m0 + mt*16 + (l >> 4)*4 + q;
        bottomBF[(size_t)row*64 + n] = (unsigned short)f2bf(acc[mt][q] + bi);
      }
    }
  }
}

// ---------------- interact: gather + Z=E·E^T (one wave per sample) --------------
// top_in row (KP4=2112): [ all_emb 0..1727 | inter 1728..2078 | pad 2079..2111 = 0 ]
__global__ __launch_bounds__(256) void interact(
    const unsigned short* __restrict__ bottomBF, const int* __restrict__ cat_idx,
    const float* __restrict__ emb, unsigned short* __restrict__ top_in){
  __shared__ unsigned short inter_s[4][352];
  int w = threadIdx.x >> 6, l = threadIdx.x & 63;
  int b = blockIdx.x * 4 + w;
  int r = l & 31, h = l >> 5;
  bool active = (r < NEMB);
  uint4v q[4];
  if(active && r == 0){
    const unsigned short* sb = bottomBF + (size_t)b * 64;
    #pragma unroll
    for(int s = 0; s < 4; s++) q[s] = *(const uint4v*)(sb + h*8 + s*16);
  } else if(active){
    int f = r - 1;
    int idx = cat_idx[b * NFEAT + f];
    const float* src = emb + ((size_t)f * VROWS + (size_t)idx) * 64;
    #pragma unroll
    for(int s = 0; s < 4; s++){
      int k0 = h*8 + s*16;
      float4 v0 = *(const float4*)(src + k0);
      float4 v1 = *(const float4*)(src + k0 + 4);
      q[s][0] = pack2(v0.x, v0.y); q[s][1] = pack2(v0.z, v0.w);
      q[s][2] = pack2(v1.x, v1.y); q[s][3] = pack2(v1.z, v1.w);
    }
  } else {
    #pragma unroll
    for(int s = 0; s < 4; s++){ q[s][0]=0; q[s][1]=0; q[s][2]=0; q[s][3]=0; }
  }
  if(active){
    #pragma unroll
    for(int s = 0; s < 4; s++)
      *(uint4v*)(top_in + (size_t)b*KP4 + r*64 + h*8 + s*16) = q[s];
  }
  f32x16 acc;
  #pragma unroll
  for(int i = 0; i < 16; i++) acc[i] = 0.f;
  #pragma unroll
  for(int s = 0; s < 4; s++){
    bf16x8 a = __builtin_bit_cast(bf16x8, q[s]);
    acc = __builtin_amdgcn_mfma_f32_32x32x16_bf16(a, a, acc, 0, 0, 0);
  }
  if(active){
    #pragma unroll
    for(int qq = 0; qq < 16; qq++){
      int i = (qq & 3) + 8*(qq >> 2) + 4*h;
      if(i < r){
        int p = i*(53 - i)/2 + (r - i - 1);
        inter_s[w][p] = (unsigned short)f2bf(acc[qq]);
      }
    }
  }
  __syncthreads();
  size_t basei = (size_t)b*KP4 + 1728;
  for(int t0 = l; t0 < 176; t0 += 64){
    uint32_t lo = inter_s[w][2*t0];
    uint32_t hi = (2*t0 + 1 < NINTER) ? (uint32_t)inter_s[w][2*t0 + 1] : 0u;
    *(uint32_t*)(top_in + basei + 2*t0) = lo | (hi << 16);
  }
  // zero pad cols 2080..2111
  if(l < 16) *(uint32_t*)(top_in + (size_t)b*KP4 + 2080 + 2*l) = 0;
}

// ---------------- gemm4: BM=256 x BN=128, 8 waves, triple-buffered deep pipeline
// 3 x 48KB LDS buffers; 6 global_load_lds (16B) per thread per K-tile;
// one barrier per K-tile; s_waitcnt vmcnt(6) keeps next tile's loads in flight.
// Both-sides XOR swizzle (pre-swizzled global src, swizzled ds_read).
template<int KSTEPS, int NB>
__global__ __launch_bounds__(512, 2) void gemm_deep(
    const unsigned short* __restrict__ A, int sA,
    const unsigned short* __restrict__ Bw, int sB,
    const float* __restrict__ bias, const float* __restrict__ gg,
    const float* __restrict__ be,
    unsigned short* __restrict__ out, int sOut){
  __shared__ char smem[3*49152];          // 3 bufs: A 32KB + B 16KB each
  int nwg = gridDim.x;
  int bid = blockIdx.x;
  int lin = (bid & 7) * (nwg >> 3) + (bid >> 3);   // XCD chunking (nwg % 8 == 0)
  int m0 = (lin / NB) * 256, n0 = (lin % NB) * 128;
  int t = threadIdx.x, w = t >> 6, l = t & 63;
  int wr = (w >> 1) * 64, wc = (w & 1) * 64;       // wave -> 64x64 of 256x128
  f32x4 acc[4][4];
  #pragma unroll
  for(int i = 0; i < 4; i++)
    #pragma unroll
    for(int j = 0; j < 4; j++)
      #pragma unroll
      for(int e = 0; e < 4; e++) acc[i][j][e] = 0.f;

  // stage assignments: i=0..3 -> A (32KB), i=4..5 -> B (16KB)
  const unsigned short* g[6];
  int ldsOff[6];
  #pragma unroll
  for(int i = 0; i < 6; i++){
    if(i < 4){
      int o = i*8192 + t*16;
      int row = o >> 7;
      int cb  = (o & 127) ^ ((row & 7) << 4);
      g[i] = A + (size_t)(m0 + row)*sA + (cb >> 1);
      ldsOff[i] = o;
    } else {
      int o = (i-4)*8192 + t*16;
      int row = o >> 7;
      int cb  = (o & 127) ^ ((row & 7) << 4);
      g[i] = Bw + (size_t)(n0 + row)*sB + (cb >> 1);
      ldsOff[i] = 32768 + o;
    }
  }
  int lr = l & 15;
  int o1 = ((l >> 4) * 16) ^ ((l & 7) << 4);

  // prologue: stage K-tiles 0 and 1
  #pragma unroll
  for(int i = 0; i < 6; i++) async_load16(g[i], smem + ldsOff[i]);
  #pragma unroll
  for(int i = 0; i < 6; i++) async_load16(g[i] + 64, smem + 49152 + ldsOff[i]);
  asm volatile("s_waitcnt vmcnt(6)" ::: "memory");
  __builtin_amdgcn_s_barrier();

  for(int kt = 0; kt < KSTEPS; kt++){
    int cur = kt % 3;
    int nxt2 = (kt + 2) % 3;
    int ksrc = (kt + 2 < KSTEPS) ? (kt + 2) : (KSTEPS - 1);  // clamped (dup, never read)
    #pragma unroll
    for(int i = 0; i < 6; i++)
      async_load16(g[i] + ksrc*64, smem + nxt2*49152 + ldsOff[i]);
    const char* bA = smem + cur*49152;
    const char* bB = bA + 32768;
    __builtin_amdgcn_s_setprio(1);
    #pragma unroll
    for(int ks = 0; ks < 2; ks++){
      int ko = o1 ^ (ks << 6);
      bf16x8 af[4], bfr[4];
      #pragma unroll
      for(int x = 0; x < 4; x++){
        af[x]  = *(const bf16x8*)(bA + (wr + x*16 + lr)*128 + ko);
        bfr[x] = *(const bf16x8*)(bB + (wc + x*16 + lr)*128 + ko);
      }
      #pragma unroll
      for(int tr = 0; tr < 4; tr++)
        #pragma unroll
        for(int tc = 0; tc < 4; tc++)
          acc[tr][tc] = __builtin_amdgcn_mfma_f32_16x16x32_bf16(af[tr], bfr[tc], acc[tr][tc], 0, 0, 0);
    }
    __builtin_amdgcn_s_setprio(0);
    asm volatile("s_waitcnt vmcnt(6)" ::: "memory");   // next tile landed; t+2 in flight
    __builtin_amdgcn_s_barrier();
  }

  #pragma unroll
  for(int tc = 0; tc < 4; tc++){
    int n = n0 + wc + tc*16 + lr;
    float sc = gg[n]*BN_INVF, bo = be[n], bi = bias[n];
    #pragma unroll
    for(int tr = 0; tr < 4; tr++){
      int mb = m0 + wr + tr*16 + (l >> 4)*4;
      #pragma unroll
      for(int qq = 0; qq < 4; qq++){
        float y = fmaxf(sc*(acc[tr][tc][qq] + bi) + bo, 0.f);
        out[(size_t)(mb + qq)*sOut + n] = (unsigned short)f2bf(y);
      }
    }
  }
}

// ---------------- MFMA GEMM: BK=64, both-sides XOR swizzle (gemm5/6) ----------
template<int KSTEPS, int NB, bool FUSE>
__global__ __launch_bounds__(256) void gemm_top(
    const unsigned short* __restrict__ A, int sA,
    const unsigned short* __restrict__ Bw, int sB,
    const float* __restrict__ bias, const float* __restrict__ gg,
    const float* __restrict__ be,
    unsigned short* __restrict__ out, int sOut,
    const float* __restrict__ W7, const float* __restrict__ b7,
    float* __restrict__ scores){
  __shared__ unsigned short As[128*64];
  __shared__ unsigned short Bs[128*64];
  __shared__ float h6s[FUSE ? 128*132 : 1];
  __shared__ float w7s[FUSE ? 128 : 1];
  int nwg = gridDim.x;
  int bid = blockIdx.x;
  int lin = (bid & 7) * (nwg >> 3) + (bid >> 3);
  int m0 = (lin / NB) * 128, n0 = (lin % NB) * 128;
  int t = threadIdx.x, w = t >> 6, l = t & 63;
  int wr = (w >> 1) * 64, wc = (w & 1) * 64;
  f32x4 acc[4][4];
  #pragma unroll
  for(int i = 0; i < 4; i++)
    #pragma unroll
    for(int j = 0; j < 4; j++)
      #pragma unroll
      for(int e = 0; e < 4; e++) acc[i][j][e] = 0.f;

  const unsigned short* gA[4];
  const unsigned short* gB[4];
  char* ldsA[4];
  char* ldsB[4];
  #pragma unroll
  for(int i = 0; i < 4; i++){
    int o   = w*4096 + i*1024 + l*16;
    int row = o >> 7;
    int cb  = (o & 127) ^ ((row & 7) << 4);
    gA[i] = A  + (size_t)(m0 + row)*sA + (cb >> 1);
    gB[i] = Bw + (size_t)(n0 + row)*sB + (cb >> 1);
    ldsA[i] = (char*)As + o;
    ldsB[i] = (char*)Bs + o;
  }
  int lr = l & 15;
  int o1 = ((l >> 4) * 16) ^ ((l & 7) << 4);

  for(int kt = 0; kt < KSTEPS; kt++){
    #pragma unroll
    for(int i = 0; i < 4; i++){
      async_load16(gA[i] + kt*64, ldsA[i]);
      async_load16(gB[i] + kt*64, ldsB[i]);
    }
    __syncthreads();
    #pragma unroll
    for(int ks = 0; ks < 2; ks++){
      int ko = o1 ^ (ks << 6);
      bf16x8 af[4], bfr[4];
      #pragma unroll
      for(int x = 0; x < 4; x++){
        af[x]  = *(const bf16x8*)((const char*)As + (wr + x*16 + lr)*128 + ko);
        bfr[x] = *(const bf16x8*)((const char*)Bs + (wc + x*16 + lr)*128 + ko);
      }
      #pragma unroll
      for(int tr = 0; tr < 4; tr++)
        #pragma unroll
        for(int tc = 0; tc < 4; tc++)
          acc[tr][tc] = __builtin_amdgcn_mfma_f32_16x16x32_bf16(af[tr], bfr[tc], acc[tr][tc], 0, 0, 0);
    }
    __syncthreads();
  }

  if constexpr(!FUSE){
    #pragma unroll
    for(int tc = 0; tc < 4; tc++){
      int n = n0 + wc + tc*16 + lr;
      float sc = gg[n]*BN_INVF, bo = be[n], bi = bias[n];
      #pragma unroll
      for(int tr = 0; tr < 4; tr++){
        int mb = m0 + wr + tr*16 + (l >> 4)*4;
        #pragma unroll
        for(int qq = 0; qq < 4; qq++){
          float y = fmaxf(sc*(acc[tr][tc][qq] + bi) + bo, 0.f);
          out[(size_t)(mb + qq)*sOut + n] = (unsigned short)f2bf(y);
        }
      }
    }
  } else {
    if(t < 128) w7s[t] = W7[t];
    #pragma unroll
    for(int tc = 0; tc < 4; tc++){
      int n = wc + tc*16 + lr;
      float sc = gg[n0+n]*BN_INVF, bo = be[n0+n], bi = bias[n0+n];
      #pragma unroll
      for(int tr = 0; tr < 4; tr++){
        int mb = wr + tr*16 + (l >> 4)*4;
        #pragma unroll
        for(int qq = 0; qq < 4; qq++)
          h6s[(mb + qq)*132 + n] = fmaxf(sc*(acc[tr][tc][qq] + bi) + bo, 0.f);
      }
    }
    __syncthreads();
    if(t < 128){
      float a7 = b7[0];
      #pragma unroll 8
      for(int c = 0; c < 128; c++) a7 = fmaf(h6s[t*132 + c], w7s[c], a7);
      scores[m0 + t] = a7;
    }
  }
}

// ---------------- launch ----------------
static inline size_t alignup(size_t x){ return (x + 255) & ~(size_t)255; }

extern "C" void kernel_launch(void* const* d_in, const int* in_sizes, int n_in,
                              void* d_out, int out_size, void* d_ws, size_t ws_size,
                              hipStream_t stream){
  const float* cont = (const float*)d_in[0];
  const int*   cat  = (const int*)  d_in[1];
  const float* emb  = (const float*)d_in[2];
  const float* W1 = (const float*)d_in[3],  *b1 = (const float*)d_in[4];
  const float* g1 = (const float*)d_in[5],  *be1= (const float*)d_in[6];
  const float* W2 = (const float*)d_in[7],  *b2 = (const float*)d_in[8];
  const float* g2 = (const float*)d_in[9],  *be2= (const float*)d_in[10];
  const float* W3 = (const float*)d_in[11], *b3 = (const float*)d_in[12];
  const float* W4 = (const float*)d_in[13], *b4 = (const float*)d_in[14];
  const float* g4 = (const float*)d_in[15], *be4= (const float*)d_in[16];
  const float* W5 = (const float*)d_in[17], *b5 = (const float*)d_in[18];
  const float* g5 = (const float*)d_in[19], *be5= (const float*)d_in[20];
  const float* W6 = (const float*)d_in[21], *b6 = (const float*)d_in[22];
  const float* g6 = (const float*)d_in[23], *be6= (const float*)d_in[24];
  const float* W7 = (const float*)d_in[25], *b7 = (const float*)d_in[26];

  char* ws = (char*)d_ws;
  unsigned short* bottomBF = (unsigned short*)ws; ws += alignup((size_t)BATCH*64*2);
  unsigned short* xphi = (unsigned short*)ws; ws += alignup((size_t)BATCH*32*2);
  unsigned short* xplo = (unsigned short*)ws; ws += alignup((size_t)BATCH*32*2);
  unsigned short* W1t  = (unsigned short*)ws; ws += alignup((size_t)256*32*2);
  unsigned short* W2t  = (unsigned short*)ws; ws += alignup((size_t)128*256*2);
  unsigned short* W3t  = (unsigned short*)ws; ws += alignup((size_t)64*128*2);
  unsigned short* topi = (unsigned short*)ws; ws += alignup((size_t)BATCH*KP4*2);
  unsigned short* W4t  = (unsigned short*)ws; ws += alignup((size_t)512*KP4*2);
  unsigned short* W5t  = (unsigned short*)ws; ws += alignup((size_t)256*512*2);
  unsigned short* W6t  = (unsigned short*)ws; ws += alignup((size_t)128*256*2);
  unsigned short* h4   = (unsigned short*)ws; ws += alignup((size_t)BATCH*512*2);
  unsigned short* h5   = (unsigned short*)ws; ws += alignup((size_t)BATCH*256*2);
  (void)ws_size; (void)n_in; (void)in_sizes; (void)out_size;

  hipLaunchKernelGGL(prep, dim3(382), dim3(256), 0, stream,
                     cont, W1, W2, W3, W4, W5, W6,
                     xphi, xplo, W1t, W2t, W3t, W4t, W5t, W6t);
  hipLaunchKernelGGL(bottom_mfma, dim3(BATCH/64), dim3(256), 0, stream,
                     xphi, xplo, W1t, W2t, W3t,
                     b1, g1, be1, b2, g2, be2, b3, bottomBF);
  hipLaunchKernelGGL(interact, dim3(BATCH/4), dim3(256), 0, stream, bottomBF, cat, emb, topi);
  hipLaunchKernelGGL((gemm_deep<33, 4>), dim3(256), dim3(512), 0, stream,
                     topi, KP4, W4t, KP4, b4, g4, be4, h4, 512);
  hipLaunchKernelGGL((gemm_top<8, 2, false>), dim3(256), dim3(256), 0, stream,
                     h4, 512, W5t, 512, b5, g5, be5, h5, 256,
                     (const float*)nullptr, (const float*)nullptr, (float*)nullptr);
  hipLaunchKernelGGL((gemm_top<4, 1, true>), dim3(128), dim3(256), 0, stream,
                     h5, 256, W6t, 256, b6, g6, be6, (unsigned short*)nullptr, 0,
                     W7, b7, (float*)d_out);
}

// Round 5
// 115.942 us; speedup vs baseline: 1.7275x; 1.0290x over previous
//
#include <hip/hip_runtime.h>
#include <stdint.h>
#include <stddef.h>

// ---------------- constants ----------------
#define BATCH   16384
#define CDIM    13
#define NFEAT   26
#define VROWS   100000
#define EDIM    64
#define NEMB    27      // bottom + 26 embeddings
#define NINTER  351     // 27*26/2
#define TOPIN   2079    // 351 + 27*64
#define KP4     2112    // padded K for layer 4 (33 x 64)
#define BN_INVF 0.9999950000374997f

typedef __attribute__((ext_vector_type(8)))  __bf16 bf16x8;
typedef __attribute__((ext_vector_type(4)))  float  f32x4;
typedef __attribute__((ext_vector_type(16))) float  f32x16;
typedef __attribute__((ext_vector_type(4)))  uint32_t uint4v;

__device__ __forceinline__ uint32_t f2bf(float f){
  uint32_t u = __float_as_uint(f);
  return (u + 0x7fffu + ((u >> 16) & 1u)) >> 16;   // RNE
}
__device__ __forceinline__ float bf2f(uint32_t h){ return __uint_as_float(h << 16); }
__device__ __forceinline__ uint32_t pack2(float a, float b){
  return f2bf(a) | (f2bf(b) << 16);
}
__device__ __forceinline__ void async_load16(const void* g, void* l){
  __builtin_amdgcn_global_load_lds(
      (const __attribute__((address_space(1))) uint32_t*)g,
      (__attribute__((address_space(3))) uint32_t*)l, 16, 0, 0);
}
// activation-LDS row swizzle (bottom_mfma, gemm_tail h5)
__device__ __forceinline__ int rswz(int row){ return ((row ^ (row >> 3)) & 7) << 3; }

// ---------------- prep: all weight transposes + x hi/lo split (one launch) ----
__device__ __forceinline__ void transpose_tile(
    float (*tile)[65], const float* __restrict__ src, unsigned short* __restrict__ dst,
    int K, int N, int Kpad, int remap, int kb, int nb){
  int k0 = kb*64, n0 = nb*64, t = threadIdx.x;
  int srcBase = remap ? ((k0 < 1728) ? (k0 + 351) : (k0 - 1728)) : k0;
  #pragma unroll 4
  for(int p = 0; p < 16; p++){
    int kr = p*4 + (t >> 6), nc = t & 63;
    float v = 0.f;
    if(k0 + kr < K && (n0 + nc) < N) v = src[(size_t)(srcBase + kr) * N + n0 + nc];
    tile[kr][nc] = v;
  }
  __syncthreads();
  #pragma unroll 4
  for(int p = 0; p < 16; p++){
    int nr = p*4 + (t >> 6), kc = t & 63;
    if(k0 + kc < Kpad && (n0 + nr) < N)
      dst[(size_t)(n0 + nr) * Kpad + k0 + kc] = (unsigned short)f2bf(tile[kc][nr]);
  }
}

__global__ __launch_bounds__(256) void prep(
    const float* __restrict__ cont,
    const float* __restrict__ W1, const float* __restrict__ W2, const float* __restrict__ W3,
    const float* __restrict__ W4, const float* __restrict__ W5, const float* __restrict__ W6,
    unsigned short* __restrict__ xphi, unsigned short* __restrict__ xplo,
    unsigned short* __restrict__ W1t, unsigned short* __restrict__ W2t,
    unsigned short* __restrict__ W3t, unsigned short* __restrict__ W4t,
    unsigned short* __restrict__ W5t, unsigned short* __restrict__ W6t){
  __shared__ float tile[64][65];
  int bid = blockIdx.x;
  if(bid < 264){ transpose_tile(tile, W4, W4t, TOPIN, 512, KP4, 1, bid % 33, bid / 33); }
  else if(bid < 296){ int r = bid-264; transpose_tile(tile, W5, W5t, 512, 256, 512, 0, r % 8, r / 8); }
  else if(bid < 304){ int r = bid-296; transpose_tile(tile, W6, W6t, 256, 128, 256, 0, r % 4, r / 4); }
  else if(bid < 312){ int r = bid-304; transpose_tile(tile, W2, W2t, 256, 128, 256, 0, r % 4, r / 4); }
  else if(bid < 314){ int r = bid-312; transpose_tile(tile, W3, W3t, 128, 64, 128, 0, r, 0); }
  else if(bid < 318){ int r = bid-314; transpose_tile(tile, W1, W1t, CDIM, 256, 32, 0, 0, r); }
  else {
    // x -> hi/lo bf16, padded 13 -> 32
    int row = (bid - 318) * 256 + threadIdx.x;
    const float* xr = cont + (size_t)row * CDIM;
    uint32_t uh[16], ul[16];
    #pragma unroll
    for(int k = 0; k < 16; k++){
      uint32_t h0=0, h1=0, l0=0, l1=0;
      if(2*k < CDIM){
        float x = xr[2*k]; h0 = f2bf(x); l0 = f2bf(x - bf2f(h0));
      }
      if(2*k+1 < CDIM){
        float x = xr[2*k+1]; h1 = f2bf(x); l1 = f2bf(x - bf2f(h1));
      }
      uh[k] = h0 | (h1 << 16);
      ul[k] = l0 | (l1 << 16);
    }
    #pragma unroll
    for(int s = 0; s < 4; s++){
      uint4v vh, vl;
      #pragma unroll
      for(int e = 0; e < 4; e++){ vh[e] = uh[4*s+e]; vl[e] = ul[4*s+e]; }
      *(uint4v*)(xphi + (size_t)row*32 + s*8) = vh;
      *(uint4v*)(xplo + (size_t)row*32 + s*8) = vl;
    }
  }
}

// ---------------- bottom MLP via MFMA, hi/lo-compensated activations ----------
__global__ __launch_bounds__(256) void bottom_mfma(
    const unsigned short* __restrict__ xphi, const unsigned short* __restrict__ xplo,
    const unsigned short* __restrict__ W1t, const unsigned short* __restrict__ W2t,
    const unsigned short* __restrict__ W3t,
    const float* __restrict__ b1, const float* __restrict__ g1, const float* __restrict__ be1,
    const float* __restrict__ b2, const float* __restrict__ g2, const float* __restrict__ be2,
    const float* __restrict__ b3,
    unsigned short* __restrict__ bottomBF){
  __shared__ unsigned short h1hi[64*256];
  __shared__ unsigned short h1lo[64*256];
  __shared__ unsigned short h2hi[64*128];
  __shared__ unsigned short h2lo[64*128];
  int t = threadIdx.x, w = t >> 6, l = t & 63;
  int m0 = blockIdx.x * 64;
  int lr = l & 15, lk = (l >> 4) * 8;

  { // layer 1: M=64, N=256, K=32
    bf16x8 axh[4], axl[4];
    #pragma unroll
    for(int mt = 0; mt < 4; mt++){
      size_t ro = (size_t)(m0 + mt*16 + lr) * 32 + lk;
      axh[mt] = *(const bf16x8*)(xphi + ro);
      axl[mt] = *(const bf16x8*)(xplo + ro);
    }
    #pragma unroll
    for(int nt = 0; nt < 4; nt++){
      int n = (w*4 + nt)*16 + lr;
      bf16x8 bw = *(const bf16x8*)(W1t + (size_t)n*32 + lk);
      f32x4 acc[4];
      #pragma unroll
      for(int mt = 0; mt < 4; mt++){
        #pragma unroll
        for(int e = 0; e < 4; e++) acc[mt][e] = 0.f;
        acc[mt] = __builtin_amdgcn_mfma_f32_16x16x32_bf16(axh[mt], bw, acc[mt], 0, 0, 0);
        acc[mt] = __builtin_amdgcn_mfma_f32_16x16x32_bf16(axl[mt], bw, acc[mt], 0, 0, 0);
      }
      float sc = g1[n]*BN_INVF, bo = be1[n], bi = b1[n];
      #pragma unroll
      for(int mt = 0; mt < 4; mt++){
        #pragma unroll
        for(int q = 0; q < 4; q++){
          int row = mt*16 + (l >> 4)*4 + q;
          float y = fmaxf(sc*(acc[mt][q] + bi) + bo, 0.f);
          uint32_t hb = f2bf(y);
          int idx = row*256 + (n ^ rswz(row));
          h1hi[idx] = (unsigned short)hb;
          h1lo[idx] = (unsigned short)f2bf(y - bf2f(hb));
        }
      }
    }
  }
  __syncthreads();

  { // layer 2: M=64, N=128, K=256
    f32x4 acc[4][2];
    #pragma unroll
    for(int mt = 0; mt < 4; mt++)
      #pragma unroll
      for(int nt = 0; nt < 2; nt++)
        #pragma unroll
        for(int e = 0; e < 4; e++) acc[mt][nt][e] = 0.f;
    for(int ks = 0; ks < 8; ks++){
      bf16x8 bw[2];
      #pragma unroll
      for(int nt = 0; nt < 2; nt++){
        int n = (w*2 + nt)*16 + lr;
        bw[nt] = *(const bf16x8*)(W2t + (size_t)n*256 + ks*32 + lk);
      }
      #pragma unroll
      for(int mt = 0; mt < 4; mt++){
        int row = mt*16 + lr;
        int idx = row*256 + ((ks*32 + lk) ^ rswz(row));
        bf16x8 ah = *(const bf16x8*)(h1hi + idx);
        bf16x8 al = *(const bf16x8*)(h1lo + idx);
        #pragma unroll
        for(int nt = 0; nt < 2; nt++){
          acc[mt][nt] = __builtin_amdgcn_mfma_f32_16x16x32_bf16(ah, bw[nt], acc[mt][nt], 0, 0, 0);
          acc[mt][nt] = __builtin_amdgcn_mfma_f32_16x16x32_bf16(al, bw[nt], acc[mt][nt], 0, 0, 0);
        }
      }
    }
    #pragma unroll
    for(int nt = 0; nt < 2; nt++){
      int n = (w*2 + nt)*16 + lr;
      float sc = g2[n]*BN_INVF, bo = be2[n], bi = b2[n];
      #pragma unroll
      for(int mt = 0; mt < 4; mt++){
        #pragma unroll
        for(int q = 0; q < 4; q++){
          int row = mt*16 + (l >> 4)*4 + q;
          float y = fmaxf(sc*(acc[mt][nt][q] + bi) + bo, 0.f);
          uint32_t hb = f2bf(y);
          int idx = row*128 + (n ^ rswz(row));
          h2hi[idx] = (unsigned short)hb;
          h2lo[idx] = (unsigned short)f2bf(y - bf2f(hb));
        }
      }
    }
  }
  __syncthreads();

  { // layer 3: M=64, N=64, K=128, no BN/ReLU
    f32x4 acc[4];
    #pragma unroll
    for(int mt = 0; mt < 4; mt++)
      #pragma unroll
      for(int e = 0; e < 4; e++) acc[mt][e] = 0.f;
    int n = w*16 + lr;
    for(int ks = 0; ks < 4; ks++){
      bf16x8 bw = *(const bf16x8*)(W3t + (size_t)n*128 + ks*32 + lk);
      #pragma unroll
      for(int mt = 0; mt < 4; mt++){
        int row = mt*16 + lr;
        int idx = row*128 + ((ks*32 + lk) ^ rswz(row));
        bf16x8 ah = *(const bf16x8*)(h2hi + idx);
        bf16x8 al = *(const bf16x8*)(h2lo + idx);
        acc[mt] = __builtin_amdgcn_mfma_f32_16x16x32_bf16(ah, bw, acc[mt], 0, 0, 0);
        acc[mt] = __builtin_amdgcn_mfma_f32_16x16x32_bf16(al, bw, acc[mt], 0, 0, 0);
      }
    }
    float bi = b3[n];
    #pragma unroll
    for(int mt = 0; mt < 4; mt++){
      #pragma unroll
      for(int q = 0; q < 4; q++){
        int row = m0 + mt*16 + (l >> 4)*4 + q;
        bottomBF[(size_t)row*64 + n] = (unsigned short)f2bf(acc[mt][q] + bi);
      }
    }
  }
}

// ---------------- interact: gather + Z=E·E^T (one wave per sample) --------------
__global__ __launch_bounds__(256) void interact(
    const unsigned short* __restrict__ bottomBF, const int* __restrict__ cat_idx,
    const float* __restrict__ emb, unsigned short* __restrict__ top_in){
  __shared__ unsigned short inter_s[4][352];
  int w = threadIdx.x >> 6, l = threadIdx.x & 63;
  int b = blockIdx.x * 4 + w;
  int r = l & 31, h = l >> 5;
  bool active = (r < NEMB);
  uint4v q[4];
  if(active && r == 0){
    const unsigned short* sb = bottomBF + (size_t)b * 64;
    #pragma unroll
    for(int s = 0; s < 4; s++) q[s] = *(const uint4v*)(sb + h*8 + s*16);
  } else if(active){
    int f = r - 1;
    int idx = cat_idx[b * NFEAT + f];
    const float* src = emb + ((size_t)f * VROWS + (size_t)idx) * 64;
    #pragma unroll
    for(int s = 0; s < 4; s++){
      int k0 = h*8 + s*16;
      float4 v0 = *(const float4*)(src + k0);
      float4 v1 = *(const float4*)(src + k0 + 4);
      q[s][0] = pack2(v0.x, v0.y); q[s][1] = pack2(v0.z, v0.w);
      q[s][2] = pack2(v1.x, v1.y); q[s][3] = pack2(v1.z, v1.w);
    }
  } else {
    #pragma unroll
    for(int s = 0; s < 4; s++){ q[s][0]=0; q[s][1]=0; q[s][2]=0; q[s][3]=0; }
  }
  if(active){
    #pragma unroll
    for(int s = 0; s < 4; s++)
      *(uint4v*)(top_in + (size_t)b*KP4 + r*64 + h*8 + s*16) = q[s];
  }
  f32x16 acc;
  #pragma unroll
  for(int i = 0; i < 16; i++) acc[i] = 0.f;
  #pragma unroll
  for(int s = 0; s < 4; s++){
    bf16x8 a = __builtin_bit_cast(bf16x8, q[s]);
    acc = __builtin_amdgcn_mfma_f32_32x32x16_bf16(a, a, acc, 0, 0, 0);
  }
  if(active){
    #pragma unroll
    for(int qq = 0; qq < 16; qq++){
      int i = (qq & 3) + 8*(qq >> 2) + 4*h;
      if(i < r){
        int p = i*(53 - i)/2 + (r - i - 1);
        inter_s[w][p] = (unsigned short)f2bf(acc[qq]);
      }
    }
  }
  __syncthreads();
  size_t basei = (size_t)b*KP4 + 1728;
  for(int t0 = l; t0 < 176; t0 += 64){
    uint32_t lo = inter_s[w][2*t0];
    uint32_t hi = (2*t0 + 1 < NINTER) ? (uint32_t)inter_s[w][2*t0 + 1] : 0u;
    *(uint32_t*)(top_in + basei + 2*t0) = lo | (hi << 16);
  }
  if(l < 16) *(uint32_t*)(top_in + (size_t)b*KP4 + 2080 + 2*l) = 0;
}

// ---------------- gemm4: 256x128, 8 waves, triple-buffer, 2-phase per K-tile --
template<int KSTEPS, int NB>
__global__ __launch_bounds__(512, 2) void gemm_deep(
    const unsigned short* __restrict__ A, int sA,
    const unsigned short* __restrict__ Bw, int sB,
    const float* __restrict__ bias, const float* __restrict__ gg,
    const float* __restrict__ be,
    unsigned short* __restrict__ out, int sOut){
  __shared__ char smem[3*49152];          // 3 bufs: A 32KB + B 16KB each
  int nwg = gridDim.x;
  int bid = blockIdx.x;
  int lin = (bid & 7) * (nwg >> 3) + (bid >> 3);   // XCD chunking (nwg % 8 == 0)
  int m0 = (lin / NB) * 256, n0 = (lin % NB) * 128;
  int t = threadIdx.x, w = t >> 6, l = t & 63;
  int wr = (w >> 1) * 64, wc = (w & 1) * 64;
  f32x4 acc[4][4];
  #pragma unroll
  for(int i = 0; i < 4; i++)
    #pragma unroll
    for(int j = 0; j < 4; j++)
      #pragma unroll
      for(int e = 0; e < 4; e++) acc[i][j][e] = 0.f;

  const unsigned short* g[6];
  int ldsOff[6];
  #pragma unroll
  for(int i = 0; i < 6; i++){
    if(i < 4){
      int o = i*8192 + t*16;
      int row = o >> 7;
      int cb  = (o & 127) ^ ((row & 7) << 4);
      g[i] = A + (size_t)(m0 + row)*sA + (cb >> 1);
      ldsOff[i] = o;
    } else {
      int o = (i-4)*8192 + t*16;
      int row = o >> 7;
      int cb  = (o & 127) ^ ((row & 7) << 4);
      g[i] = Bw + (size_t)(n0 + row)*sB + (cb >> 1);
      ldsOff[i] = 32768 + o;
    }
  }
  int lr = l & 15;
  int o1 = ((l >> 4) * 16) ^ ((l & 7) << 4);

  // prologue: stage K-tiles 0 and 1
  #pragma unroll
  for(int i = 0; i < 6; i++) async_load16(g[i], smem + ldsOff[i]);
  #pragma unroll
  for(int i = 0; i < 6; i++) async_load16(g[i] + 64, smem + 49152 + ldsOff[i]);
  asm volatile("s_waitcnt vmcnt(6)" ::: "memory");
  __builtin_amdgcn_s_barrier();

  for(int kt = 0; kt < KSTEPS; kt++){
    int cur = kt % 3;
    int nxt2 = (kt + 2) % 3;
    int ksrc = (kt + 2 < KSTEPS) ? (kt + 2) : (KSTEPS - 1);  // clamped dup, never read
    const char* bA = smem + cur*49152;
    const char* bB = bA + 32768;
    // ---- phase 0 (ks = 0) ----
    #pragma unroll
    for(int i = 0; i < 3; i++)
      async_load16(g[i] + ksrc*64, smem + nxt2*49152 + ldsOff[i]);
    {
      bf16x8 af[4], bfr[4];
      #pragma unroll
      for(int x = 0; x < 4; x++){
        af[x]  = *(const bf16x8*)(bA + (wr + x*16 + lr)*128 + o1);
        bfr[x] = *(const bf16x8*)(bB + (wc + x*16 + lr)*128 + o1);
      }
      __builtin_amdgcn_s_barrier();
      __builtin_amdgcn_s_setprio(1);
      #pragma unroll
      for(int tr = 0; tr < 4; tr++)
        #pragma unroll
        for(int tc = 0; tc < 4; tc++)
          acc[tr][tc] = __builtin_amdgcn_mfma_f32_16x16x32_bf16(af[tr], bfr[tc], acc[tr][tc], 0, 0, 0);
      __builtin_amdgcn_s_setprio(0);
    }
    __builtin_amdgcn_s_barrier();
    // ---- phase 1 (ks = 1) ----
    #pragma unroll
    for(int i = 3; i < 6; i++)
      async_load16(g[i] + ksrc*64, smem + nxt2*49152 + ldsOff[i]);
    {
      bf16x8 af[4], bfr[4];
      int ko = o1 ^ 64;
      #pragma unroll
      for(int x = 0; x < 4; x++){
        af[x]  = *(const bf16x8*)(bA + (wr + x*16 + lr)*128 + ko);
        bfr[x] = *(const bf16x8*)(bB + (wc + x*16 + lr)*128 + ko);
      }
      asm volatile("s_waitcnt vmcnt(6)" ::: "memory");   // kt+1 landed; kt+2 in flight
      __builtin_amdgcn_s_barrier();
      __builtin_amdgcn_s_setprio(1);
      #pragma unroll
      for(int tr = 0; tr < 4; tr++)
        #pragma unroll
        for(int tc = 0; tc < 4; tc++)
          acc[tr][tc] = __builtin_amdgcn_mfma_f32_16x16x32_bf16(af[tr], bfr[tc], acc[tr][tc], 0, 0, 0);
      __builtin_amdgcn_s_setprio(0);
    }
    __builtin_amdgcn_s_barrier();
  }

  #pragma unroll
  for(int tc = 0; tc < 4; tc++){
    int n = n0 + wc + tc*16 + lr;
    float sc = gg[n]*BN_INVF, bo = be[n], bi = bias[n];
    #pragma unroll
    for(int tr = 0; tr < 4; tr++){
      int mb = m0 + wr + tr*16 + (l >> 4)*4;
      #pragma unroll
      for(int qq = 0; qq < 4; qq++){
        float y = fmaxf(sc*(acc[tr][tc][qq] + bi) + bo, 0.f);
        out[(size_t)(mb + qq)*sOut + n] = (unsigned short)f2bf(y);
      }
    }
  }
}

// ---------------- gemm_tail: layers 5+6+7 fused, 64 rows/block, 4 waves -------
// LDS: [0,8K) A-stage | [8K,40K) B-stage | [40K,72K) h5 | [72K,+1K) pscore
__global__ __launch_bounds__(256) void gemm_tail(
    const unsigned short* __restrict__ h4,      // [BATCH][512]
    const unsigned short* __restrict__ W5t,     // [256][512]
    const float* __restrict__ b5, const float* __restrict__ g5, const float* __restrict__ be5,
    const unsigned short* __restrict__ W6t,     // [128][256]
    const float* __restrict__ b6, const float* __restrict__ g6, const float* __restrict__ be6,
    const float* __restrict__ W7, const float* __restrict__ b7,
    float* __restrict__ scores){
  __shared__ char smem[74752];
  unsigned short* h5 = (unsigned short*)(smem + 40960);
  float* pscore = (float*)(smem + 73728);
  int t = threadIdx.x, w = t >> 6, l = t & 63;
  int m0 = blockIdx.x * 64;
  int lr = l & 15;
  int o1 = ((l >> 4) * 16) ^ ((l & 7) << 4);

  // ---- L5: 64x256, K=512 (8 steps of 64), single-buffer 2-barrier ----
  f32x4 acc5[4][4];
  #pragma unroll
  for(int i = 0; i < 4; i++)
    #pragma unroll
    for(int j = 0; j < 4; j++)
      #pragma unroll
      for(int e = 0; e < 4; e++) acc5[i][j][e] = 0.f;

  const unsigned short* gA[2]; int ldsA[2];
  #pragma unroll
  for(int i = 0; i < 2; i++){
    int o = i*4096 + t*16;
    int row = o >> 7;
    int cb = (o & 127) ^ ((row & 7) << 4);
    gA[i] = h4 + (size_t)(m0 + row)*512 + (cb >> 1);
    ldsA[i] = o;
  }
  const unsigned short* gB[8]; int ldsB[8];
  #pragma unroll
  for(int i = 0; i < 8; i++){
    int o = i*4096 + t*16;
    int row = o >> 7;
    int cb = (o & 127) ^ ((row & 7) << 4);
    gB[i] = W5t + (size_t)row*512 + (cb >> 1);
    ldsB[i] = 8192 + o;
  }

  for(int kt = 0; kt < 8; kt++){
    #pragma unroll
    for(int i = 0; i < 2; i++) async_load16(gA[i] + kt*64, smem + ldsA[i]);
    #pragma unroll
    for(int i = 0; i < 8; i++) async_load16(gB[i] + kt*64, smem + ldsB[i]);
    __syncthreads();
    #pragma unroll
    for(int ks = 0; ks < 2; ks++){
      int ko = o1 ^ (ks << 6);
      bf16x8 af[4], bfr[4];
      #pragma unroll
      for(int x = 0; x < 4; x++){
        af[x]  = *(const bf16x8*)(smem + (x*16 + lr)*128 + ko);
        bfr[x] = *(const bf16x8*)(smem + 8192 + (w*64 + x*16 + lr)*128 + ko);
      }
      #pragma unroll
      for(int tr = 0; tr < 4; tr++)
        #pragma unroll
        for(int tc = 0; tc < 4; tc++)
          acc5[tr][tc] = __builtin_amdgcn_mfma_f32_16x16x32_bf16(af[tr], bfr[tc], acc5[tr][tc], 0, 0, 0);
    }
    __syncthreads();
  }

  // stage W6t k-half 0 into [0,32K) (A/B regions dead) — overlaps h5 epilogue
  #pragma unroll
  for(int i = 0; i < 8; i++){
    int o = i*4096 + t*16;
    int row = o >> 8;
    int cb = (o & 255) ^ ((row & 15) << 4);
    async_load16(W6t + (size_t)row*256 + (cb >> 1), smem + o);
  }
  // L5 epilogue -> h5 (row-swizzled)
  #pragma unroll
  for(int tc = 0; tc < 4; tc++){
    int c = w*64 + tc*16 + lr;
    float sc = g5[c]*BN_INVF, bo = be5[c], bi = b5[c];
    #pragma unroll
    for(int tr = 0; tr < 4; tr++){
      #pragma unroll
      for(int qq = 0; qq < 4; qq++){
        int row = tr*16 + (l >> 4)*4 + qq;
        float y = fmaxf(sc*(acc5[tr][tc][qq] + bi) + bo, 0.f);
        h5[row*256 + (c ^ rswz(row))] = (unsigned short)f2bf(y);
      }
    }
  }
  __syncthreads();   // h5 visible; W6t half-0 landed (full drain)

  // ---- L6: 64x128, K=256 in 2 halves of 128 ----
  f32x4 acc6[4][2];
  #pragma unroll
  for(int i = 0; i < 4; i++)
    #pragma unroll
    for(int j = 0; j < 2; j++)
      #pragma unroll
      for(int e = 0; e < 4; e++) acc6[i][j][e] = 0.f;
  int lk = (l >> 4) * 8;          // elems
  int lk2 = (l >> 4) * 16;        // bytes
  #pragma unroll
  for(int half = 0; half < 2; half++){
    if(half == 1){
      __syncthreads();            // all half-0 reads done
      #pragma unroll
      for(int i = 0; i < 8; i++){
        int o = i*4096 + t*16;
        int row = o >> 8;
        int cb = (o & 255) ^ ((row & 15) << 4);
        async_load16(W6t + (size_t)row*256 + 128 + (cb >> 1), smem + o);
      }
      __syncthreads();            // landed
    }
    #pragma unroll
    for(int ks = 0; ks < 4; ks++){
      bf16x8 af6[4], bfr6[2];
      #pragma unroll
      for(int mt = 0; mt < 4; mt++){
        int row = mt*16 + lr;
        af6[mt] = *(const bf16x8*)(h5 + row*256 + ((half*128 + ks*32 + lk) ^ rswz(row)));
      }
      #pragma unroll
      for(int nt = 0; nt < 2; nt++){
        int row = w*32 + nt*16 + lr;
        bfr6[nt] = *(const bf16x8*)(smem + row*256 + ((ks*64 + lk2) ^ (lr << 4)));
      }
      #pragma unroll
      for(int mt = 0; mt < 4; mt++)
        #pragma unroll
        for(int nt = 0; nt < 2; nt++)
          acc6[mt][nt] = __builtin_amdgcn_mfma_f32_16x16x32_bf16(af6[mt], bfr6[nt], acc6[mt][nt], 0, 0, 0);
    }
  }

  // ---- L6 epilogue + L7 dot (shuffle-tree over 16 cols, LDS over waves) ----
  float pr[16];
  #pragma unroll
  for(int nt = 0; nt < 2; nt++){
    int c = w*32 + nt*16 + lr;
    float sc = g6[c]*BN_INVF, bo = be6[c], bi = b6[c];
    float w7c = W7[c];
    #pragma unroll
    for(int mt = 0; mt < 4; mt++){
      #pragma unroll
      for(int qq = 0; qq < 4; qq++){
        float v = fmaxf(sc*(acc6[mt][nt][qq] + bi) + bo, 0.f) * w7c;
        if(nt == 0) pr[mt*4 + qq] = v; else pr[mt*4 + qq] += v;
      }
    }
  }
  #pragma unroll
  for(int mask = 1; mask < 16; mask <<= 1){
    #pragma unroll
    for(int i = 0; i < 16; i++) pr[i] += __shfl_xor(pr[i], mask, 64);
  }
  if(lr == 0){
    #pragma unroll
    for(int mt = 0; mt < 4; mt++)
      #pragma unroll
      for(int qq = 0; qq < 4; qq++)
        pscore[w*64 + mt*16 + (l >> 4)*4 + qq] = pr[mt*4 + qq];
  }
  __syncthreads();
  if(t < 64){
    float s = b7[0] + pscore[t] + pscore[64 + t] + pscore[128 + t] + pscore[192 + t];
    scores[m0 + t] = s;
  }
}

// ---------------- launch ----------------
static inline size_t alignup(size_t x){ return (x + 255) & ~(size_t)255; }

extern "C" void kernel_launch(void* const* d_in, const int* in_sizes, int n_in,
                              void* d_out, int out_size, void* d_ws, size_t ws_size,
                              hipStream_t stream){
  const float* cont = (const float*)d_in[0];
  const int*   cat  = (const int*)  d_in[1];
  const float* emb  = (const float*)d_in[2];
  const float* W1 = (const float*)d_in[3],  *b1 = (const float*)d_in[4];
  const float* g1 = (const float*)d_in[5],  *be1= (const float*)d_in[6];
  const float* W2 = (const float*)d_in[7],  *b2 = (const float*)d_in[8];
  const float* g2 = (const float*)d_in[9],  *be2= (const float*)d_in[10];
  const float* W3 = (const float*)d_in[11], *b3 = (const float*)d_in[12];
  const float* W4 = (const float*)d_in[13], *b4 = (const float*)d_in[14];
  const float* g4 = (const float*)d_in[15], *be4= (const float*)d_in[16];
  const float* W5 = (const float*)d_in[17], *b5 = (const float*)d_in[18];
  const float* g5 = (const float*)d_in[19], *be5= (const float*)d_in[20];
  const float* W6 = (const float*)d_in[21], *b6 = (const float*)d_in[22];
  const float* g6 = (const float*)d_in[23], *be6= (const float*)d_in[24];
  const float* W7 = (const float*)d_in[25], *b7 = (const float*)d_in[26];

  char* ws = (char*)d_ws;
  unsigned short* bottomBF = (unsigned short*)ws; ws += alignup((size_t)BATCH*64*2);
  unsigned short* xphi = (unsigned short*)ws; ws += alignup((size_t)BATCH*32*2);
  unsigned short* xplo = (unsigned short*)ws; ws += alignup((size_t)BATCH*32*2);
  unsigned short* W1t  = (unsigned short*)ws; ws += alignup((size_t)256*32*2);
  unsigned short* W2t  = (unsigned short*)ws; ws += alignup((size_t)128*256*2);
  unsigned short* W3t  = (unsigned short*)ws; ws += alignup((size_t)64*128*2);
  unsigned short* topi = (unsigned short*)ws; ws += alignup((size_t)BATCH*KP4*2);
  unsigned short* W4t  = (unsigned short*)ws; ws += alignup((size_t)512*KP4*2);
  unsigned short* W5t  = (unsigned short*)ws; ws += alignup((size_t)256*512*2);
  unsigned short* W6t  = (unsigned short*)ws; ws += alignup((size_t)128*256*2);
  unsigned short* h4   = (unsigned short*)ws; ws += alignup((size_t)BATCH*512*2);
  (void)ws_size; (void)n_in; (void)in_sizes; (void)out_size;

  hipLaunchKernelGGL(prep, dim3(382), dim3(256), 0, stream,
                     cont, W1, W2, W3, W4, W5, W6,
                     xphi, xplo, W1t, W2t, W3t, W4t, W5t, W6t);
  hipLaunchKernelGGL(bottom_mfma, dim3(BATCH/64), dim3(256), 0, stream,
                     xphi, xplo, W1t, W2t, W3t,
                     b1, g1, be1, b2, g2, be2, b3, bottomBF);
  hipLaunchKernelGGL(interact, dim3(BATCH/4), dim3(256), 0, stream, bottomBF, cat, emb, topi);
  hipLaunchKernelGGL((gemm_deep<33, 4>), dim3(256), dim3(512), 0, stream,
                     topi, KP4, W4t, KP4, b4, g4, be4, h4, 512);
  hipLaunchKernelGGL(gemm_tail, dim3(256), dim3(256), 0, stream,
                     h4, W5t, b5, g5, be5, W6t, b6, g6, be6, W7, b7, (float*)d_out);
}